// Round 2
// baseline (222.730 us; speedup 1.0000x reference)
//
#include <hip/hip_runtime.h>
#include <hip/hip_bf16.h>

// MultiHeadAttention B=4 S=2048 E=512 H=8 D=64, causal.
// Inputs fp32, OUTPUT fp32 (round-1 forensics: out npz = 15.56MB => fp32).
// 3-kernel bf16-MFMA pipeline:
//   proj: X @ W^T per head (shared W), writes Qp/Kp [bh][s][d] and Vt [bh][d][s] (transposed)
//   attn: flash attention, 64 q-rows/block, online softmax in-register
//   fc:   [8192,512] @ Wfc^T + bias -> fp32 out
// ws usage: 4 x 8 MiB bf16 buffers (Qp, Kp, Vt, Oattn) = 33.6 MB.

#define S_LEN 2048
#define EMB 512
#define NH 8
#define HD 64

typedef __bf16 bf16x8 __attribute__((ext_vector_type(8)));
typedef __bf16 bf16x4 __attribute__((ext_vector_type(4)));
typedef float f32x4 __attribute__((ext_vector_type(4)));

// XOR swizzle: permutes 16B slots within a 128B row -> conflict-free ds_read_b128
// for 16-lane column-slice reads (guide §6 G4). Applied identically on write+read.
__device__ __forceinline__ unsigned swz(unsigned byteoff, unsigned row) {
    return byteoff ^ ((row & 7u) << 4);
}

__global__ __launch_bounds__(256) void proj_kernel(
    const float* __restrict__ qin, const float* __restrict__ kin, const float* __restrict__ vin,
    const float* __restrict__ Wq, const float* __restrict__ Wk, const float* __restrict__ Wv,
    __bf16* __restrict__ Qp, __bf16* __restrict__ Kp, __bf16* __restrict__ Vt)
{
    __shared__ alignas(16) unsigned char xb[3][8192]; // 64x64 bf16 tiles (q,k,v rows), swizzled
    __shared__ alignas(16) unsigned char tb[8192];    // v-proj output tile for transpose, linear
    const int bh = blockIdx.y;
    const int b = bh >> 3, h = bh & 7;
    const int sblk = blockIdx.x << 6;
    const int tid = threadIdx.x;
    const int w = tid >> 6, l = tid & 63;
    const int col = l & 15, g = l >> 4;

    const float* srcs[3] = {qin, kin, vin};
    #pragma unroll
    for (int p = 0; p < 3; ++p) {
        const float* src = srcs[p] + ((size_t)b * S_LEN + sblk) * EMB + h * HD;
        #pragma unroll
        for (int it = 0; it < 4; ++it) {
            int c = tid + it * 256;            // 1024 float4 chunks = 64 rows x 16
            int row = c >> 4, c4 = c & 15;
            float4 f = *reinterpret_cast<const float4*>(src + (size_t)row * EMB + c4 * 4);
            bf16x4 t;
            t[0] = (__bf16)f.x; t[1] = (__bf16)f.y; t[2] = (__bf16)f.z; t[3] = (__bf16)f.w;
            *reinterpret_cast<bf16x4*>(&xb[p][swz(row * 128 + c4 * 8, row)]) = t;
        }
    }
    __syncthreads();

    const float* Ws[3] = {Wq, Wk, Wv};
    #pragma unroll
    for (int p = 0; p < 3; ++p) {
        // B-frags of W: lane holds W[e = 16*nf + col][k = ks*32 + 8*g .. +8]
        bf16x8 wf[4][2];
        #pragma unroll
        for (int nf = 0; nf < 4; ++nf)
            #pragma unroll
            for (int ks = 0; ks < 2; ++ks) {
                const float* base = Ws[p] + (nf * 16 + col) * HD + ks * 32 + g * 8;
                float4 f0 = *reinterpret_cast<const float4*>(base);
                float4 f1 = *reinterpret_cast<const float4*>(base + 4);
                bf16x8 r;
                r[0] = (__bf16)f0.x; r[1] = (__bf16)f0.y; r[2] = (__bf16)f0.z; r[3] = (__bf16)f0.w;
                r[4] = (__bf16)f1.x; r[5] = (__bf16)f1.y; r[6] = (__bf16)f1.z; r[7] = (__bf16)f1.w;
                wf[nf][ks] = r;
            }
        // A-frags: wave w owns s-rows w*16..w*16+15
        int arow = w * 16 + col;
        bf16x8 a0 = *reinterpret_cast<const bf16x8*>(&xb[p][swz(arow * 128 + g * 16, arow)]);
        bf16x8 a1 = *reinterpret_cast<const bf16x8*>(&xb[p][swz(arow * 128 + 64 + g * 16, arow)]);
        f32x4 acc[4];
        #pragma unroll
        for (int nf = 0; nf < 4; ++nf) acc[nf] = (f32x4){0.f, 0.f, 0.f, 0.f};
        #pragma unroll
        for (int nf = 0; nf < 4; ++nf) {
            acc[nf] = __builtin_amdgcn_mfma_f32_16x16x32_bf16(a0, wf[nf][0], acc[nf], 0, 0, 0);
            acc[nf] = __builtin_amdgcn_mfma_f32_16x16x32_bf16(a1, wf[nf][1], acc[nf], 0, 0, 0);
        }
        if (p < 2) {
            __bf16* dst = (p == 0 ? Qp : Kp);
            #pragma unroll
            for (int nf = 0; nf < 4; ++nf)
                #pragma unroll
                for (int r = 0; r < 4; ++r) {
                    int srow = sblk + w * 16 + g * 4 + r;
                    dst[((size_t)bh * S_LEN + srow) * HD + nf * 16 + col] = (__bf16)acc[nf][r];
                }
        } else {
            // v-proj -> LDS tile [s_local][e] for transposed global write
            #pragma unroll
            for (int nf = 0; nf < 4; ++nf)
                #pragma unroll
                for (int r = 0; r < 4; ++r) {
                    int srow = w * 16 + g * 4 + r;
                    *reinterpret_cast<__bf16*>(&tb[(srow * 64 + nf * 16 + col) * 2]) =
                        (__bf16)acc[nf][r];
                }
        }
    }
    __syncthreads();
    // transposed, coalesced write of Vt[bh][e][s]
    {
        int e = tid & 63, sc = tid >> 6;
        bf16x8 lo, hi;
        #pragma unroll
        for (int i = 0; i < 8; ++i)
            lo[i] = *reinterpret_cast<const __bf16*>(&tb[((sc * 16 + i) * 64 + e) * 2]);
        #pragma unroll
        for (int i = 0; i < 8; ++i)
            hi[i] = *reinterpret_cast<const __bf16*>(&tb[((sc * 16 + 8 + i) * 64 + e) * 2]);
        __bf16* dst = Vt + ((size_t)bh * HD + e) * S_LEN + sblk + sc * 16;
        *reinterpret_cast<bf16x8*>(dst) = lo;
        *reinterpret_cast<bf16x8*>(dst + 8) = hi;
    }
}

__global__ __launch_bounds__(256) void attn_kernel(
    const __bf16* __restrict__ Qp, const __bf16* __restrict__ Kp,
    const __bf16* __restrict__ Vt, __bf16* __restrict__ Oa)
{
    __shared__ alignas(16) unsigned char kb[8192];     // K tile [kv_row][d], swizzled
    __shared__ alignas(16) unsigned char vb[8192];     // V tile [d][kv_row], swizzled
    __shared__ alignas(16) unsigned char pb[4][2048];  // per-wave P tile [16][64], swizzled
    const int bh = blockIdx.y;
    const int b = bh >> 3, h = bh & 7;
    const int qt = blockIdx.x;
    const int tid = threadIdx.x;
    const int w = tid >> 6, l = tid & 63;
    const int col = l & 15, g = l >> 4;

    // Q A-frags held in registers for the whole block
    bf16x8 qf0, qf1;
    {
        const __bf16* qb = Qp + ((size_t)bh * S_LEN + qt * 64 + w * 16 + col) * HD + g * 8;
        qf0 = *reinterpret_cast<const bf16x8*>(qb);
        qf1 = *reinterpret_cast<const bf16x8*>(qb + 32);
    }
    f32x4 oacc[4];
    #pragma unroll
    for (int nf = 0; nf < 4; ++nf) oacc[nf] = (f32x4){0.f, 0.f, 0.f, 0.f};
    float m[4], lsum[4];
    #pragma unroll
    for (int r = 0; r < 4; ++r) { m[r] = -1e30f; lsum[r] = 0.f; }

    const float K1 = 0.18033688011112042f; // log2(e)/8 : softmax in exp2 domain, scale folded
    const int nt = qt + 1;                 // causal: only tiles with kv <= q
    for (int t = 0; t < nt; ++t) {
        __syncthreads(); // previous tile's LDS reads done before restage
        {
            const unsigned char* kg =
                reinterpret_cast<const unsigned char*>(Kp + ((size_t)bh * S_LEN + t * 64) * HD);
            #pragma unroll
            for (int it = 0; it < 2; ++it) {
                int c = tid + it * 256;
                int row = c >> 3, o = (c & 7) * 16;
                uint4 d = *reinterpret_cast<const uint4*>(kg + row * 128 + o);
                *reinterpret_cast<uint4*>(&kb[swz(row * 128 + o, row)]) = d;
            }
            const unsigned char* vg =
                reinterpret_cast<const unsigned char*>(Vt + (size_t)bh * HD * S_LEN + t * 64);
            #pragma unroll
            for (int it = 0; it < 2; ++it) {
                int c = tid + it * 256;
                int row = c >> 3, o = (c & 7) * 16;
                uint4 d = *reinterpret_cast<const uint4*>(vg + (size_t)row * (S_LEN * 2) + o);
                *reinterpret_cast<uint4*>(&vb[swz(row * 128 + o, row)]) = d;
            }
        }
        __syncthreads();
        // S = Q K^T (16 q-rows per wave x 64 kv-cols)
        f32x4 sf[4];
        #pragma unroll
        for (int nf = 0; nf < 4; ++nf) sf[nf] = (f32x4){0.f, 0.f, 0.f, 0.f};
        #pragma unroll
        for (int nf = 0; nf < 4; ++nf) {
            int krow = nf * 16 + col;
            bf16x8 kf0 = *reinterpret_cast<const bf16x8*>(&kb[swz(krow * 128 + g * 16, krow)]);
            bf16x8 kf1 = *reinterpret_cast<const bf16x8*>(&kb[swz(krow * 128 + 64 + g * 16, krow)]);
            sf[nf] = __builtin_amdgcn_mfma_f32_16x16x32_bf16(qf0, kf0, sf[nf], 0, 0, 0);
            sf[nf] = __builtin_amdgcn_mfma_f32_16x16x32_bf16(qf1, kf1, sf[nf], 0, 0, 0);
        }
        if (t == qt) { // diagonal tile: causal mask (matches ref: mask applied pre-scale)
            #pragma unroll
            for (int nf = 0; nf < 4; ++nf)
                #pragma unroll
                for (int r = 0; r < 4; ++r) {
                    int cg = t * 64 + nf * 16 + col;
                    int rg = qt * 64 + w * 16 + g * 4 + r;
                    if (cg > rg) sf[nf][r] = -1e30f;
                }
        }
        // online softmax, exp2 domain; C/D layout: lane holds rows 4*g+r, col = 16*nf+col
        float rmax[4];
        #pragma unroll
        for (int r = 0; r < 4; ++r)
            rmax[r] = fmaxf(fmaxf(sf[0][r], sf[1][r]), fmaxf(sf[2][r], sf[3][r])) * K1;
        #pragma unroll
        for (int d = 1; d < 16; d <<= 1) {
            #pragma unroll
            for (int r = 0; r < 4; ++r) rmax[r] = fmaxf(rmax[r], __shfl_xor(rmax[r], d));
        }
        float sc[4], rsum[4];
        #pragma unroll
        for (int r = 0; r < 4; ++r) {
            float mn = fmaxf(m[r], rmax[r]);
            sc[r] = __builtin_exp2f(m[r] - mn);
            m[r] = mn;
            rsum[r] = 0.f;
        }
        #pragma unroll
        for (int nf = 0; nf < 4; ++nf) {
            #pragma unroll
            for (int r = 0; r < 4; ++r) {
                float p = __builtin_exp2f(sf[nf][r] * K1 - m[r]);
                rsum[r] += p;
                int prow = g * 4 + r;
                *reinterpret_cast<__bf16*>(
                    &pb[w][swz(prow * 128 + (nf * 16 + col) * 2, prow)]) = (__bf16)p;
            }
        }
        #pragma unroll
        for (int d = 1; d < 16; d <<= 1) {
            #pragma unroll
            for (int r = 0; r < 4; ++r) rsum[r] += __shfl_xor(rsum[r], d);
        }
        #pragma unroll
        for (int r = 0; r < 4; ++r) lsum[r] = lsum[r] * sc[r] + rsum[r];
        #pragma unroll
        for (int nf = 0; nf < 4; ++nf)
            #pragma unroll
            for (int r = 0; r < 4; ++r) oacc[nf][r] *= sc[r];
        __syncthreads(); // P LDS write -> read fence (also orders with staging)
        // O += P V : A-frag = P rows (lane&15), B-frag = Vt rows d
        bf16x8 pf0 = *reinterpret_cast<const bf16x8*>(&pb[w][swz(col * 128 + g * 16, col)]);
        bf16x8 pf1 = *reinterpret_cast<const bf16x8*>(&pb[w][swz(col * 128 + 64 + g * 16, col)]);
        #pragma unroll
        for (int nf = 0; nf < 4; ++nf) {
            int vrow = nf * 16 + col;
            bf16x8 vf0 = *reinterpret_cast<const bf16x8*>(&vb[swz(vrow * 128 + g * 16, vrow)]);
            bf16x8 vf1 = *reinterpret_cast<const bf16x8*>(&vb[swz(vrow * 128 + 64 + g * 16, vrow)]);
            oacc[nf] = __builtin_amdgcn_mfma_f32_16x16x32_bf16(pf0, vf0, oacc[nf], 0, 0, 0);
            oacc[nf] = __builtin_amdgcn_mfma_f32_16x16x32_bf16(pf1, vf1, oacc[nf], 0, 0, 0);
        }
    }
    #pragma unroll
    for (int r = 0; r < 4; ++r) lsum[r] = 1.0f / lsum[r];
    #pragma unroll
    for (int nf = 0; nf < 4; ++nf)
        #pragma unroll
        for (int r = 0; r < 4; ++r) {
            int s = qt * 64 + w * 16 + g * 4 + r;
            Oa[((size_t)b * S_LEN + s) * EMB + h * HD + nf * 16 + col] =
                (__bf16)(oacc[nf][r] * lsum[r]);
        }
}

__global__ __launch_bounds__(256) void fc_kernel(
    const __bf16* __restrict__ A,   // Oattn [B*S][E] bf16
    const float* __restrict__ Wfc,  // [E][E] fp32, row-major (n, k)
    const float* __restrict__ bfc,  // [E]
    float* __restrict__ out)        // [B*S][E] fp32
{
    __shared__ alignas(16) unsigned char ab[8192]; // A tile 64x64 bf16, swizzled
    __shared__ alignas(16) unsigned char bb[8192]; // W tile 64x64 bf16, swizzled
    const int r0 = blockIdx.x << 6;
    const int n0 = blockIdx.y << 6;
    const int tid = threadIdx.x;
    const int w = tid >> 6, l = tid & 63;
    const int col = l & 15, g = l >> 4;

    f32x4 acc[4];
    #pragma unroll
    for (int nf = 0; nf < 4; ++nf) acc[nf] = (f32x4){0.f, 0.f, 0.f, 0.f};

    for (int kc = 0; kc < 8; ++kc) {
        __syncthreads();
        #pragma unroll
        for (int it = 0; it < 2; ++it) { // A tile: 512 uint4 chunks
            int c = tid + it * 256;
            int row = c >> 3, o = (c & 7) * 16;
            uint4 d = *reinterpret_cast<const uint4*>(
                reinterpret_cast<const unsigned char*>(A) +
                ((size_t)(r0 + row) * EMB + kc * 64) * 2 + o);
            *reinterpret_cast<uint4*>(&ab[swz(row * 128 + o, row)]) = d;
        }
        #pragma unroll
        for (int it = 0; it < 4; ++it) { // W tile: 1024 float4 chunks, cvt to bf16
            int c = tid + it * 256;
            int row = c >> 4, c4 = c & 15;
            float4 f = *reinterpret_cast<const float4*>(
                Wfc + (size_t)(n0 + row) * EMB + kc * 64 + c4 * 4);
            bf16x4 t;
            t[0] = (__bf16)f.x; t[1] = (__bf16)f.y; t[2] = (__bf16)f.z; t[3] = (__bf16)f.w;
            *reinterpret_cast<bf16x4*>(&bb[swz(row * 128 + c4 * 8, row)]) = t;
        }
        __syncthreads();
        int arow = w * 16 + col;
        #pragma unroll
        for (int ks = 0; ks < 2; ++ks) {
            bf16x8 af = *reinterpret_cast<const bf16x8*>(
                &ab[swz(arow * 128 + ks * 64 + g * 16, arow)]);
            #pragma unroll
            for (int nf = 0; nf < 4; ++nf) {
                int brow = nf * 16 + col;
                bf16x8 bf = *reinterpret_cast<const bf16x8*>(
                    &bb[swz(brow * 128 + ks * 64 + g * 16, brow)]);
                acc[nf] = __builtin_amdgcn_mfma_f32_16x16x32_bf16(af, bf, acc[nf], 0, 0, 0);
            }
        }
    }
    #pragma unroll
    for (int nf = 0; nf < 4; ++nf) {
        float bias = bfc[n0 + nf * 16 + col];
        #pragma unroll
        for (int r = 0; r < 4; ++r) {
            int row = r0 + w * 16 + g * 4 + r;
            out[(size_t)row * EMB + n0 + nf * 16 + col] = acc[nf][r] + bias;
        }
    }
}

extern "C" void kernel_launch(void* const* d_in, const int* in_sizes, int n_in,
                              void* d_out, int out_size, void* d_ws, size_t ws_size,
                              hipStream_t stream) {
    const float* q   = (const float*)d_in[0];
    const float* k   = (const float*)d_in[1];
    const float* v   = (const float*)d_in[2];
    const float* Wq  = (const float*)d_in[3];
    const float* Wk  = (const float*)d_in[4];
    const float* Wv  = (const float*)d_in[5];
    const float* Wfc = (const float*)d_in[6];
    const float* bfc = (const float*)d_in[7];
    // d_in[8] = mask: causal tril, hardcoded in attn_kernel.
    float* out = (float*)d_out;

    char* ws = (char*)d_ws;
    const size_t SZ = (size_t)4 * NH * S_LEN * HD * sizeof(__bf16); // 8 MiB
    __bf16* Qp = (__bf16*)(ws);
    __bf16* Kp = (__bf16*)(ws + SZ);
    __bf16* Vt = (__bf16*)(ws + 2 * SZ);
    __bf16* Oa = (__bf16*)(ws + 3 * SZ);

    proj_kernel<<<dim3(S_LEN / 64, 4 * NH), 256, 0, stream>>>(q, k, v, Wq, Wk, Wv, Qp, Kp, Vt);
    attn_kernel<<<dim3(S_LEN / 64, 4 * NH), 256, 0, stream>>>(Qp, Kp, Vt, Oa);
    fc_kernel<<<dim3((4 * S_LEN) / 64, EMB / 64), 256, 0, stream>>>(Oa, Wfc, bfc, out);
}

// Round 3
// 132.897 us; speedup vs baseline: 1.6760x; 1.6760x over previous
//
#include <hip/hip_runtime.h>
#include <hip/hip_bf16.h>

// MultiHeadAttention B=4 S=2048 E=512 H=8 D=64, causal. Inputs fp32, output fp32.
// 3-kernel bf16-MFMA pipeline:
//   proj: X @ W^T per head (shared W), writes Qp/Kp [bh][s][d] and Vt [bh][d][s]
//   attn: flash attention, diagonal-paired q-tiles {i, 31-i} for causal load balance,
//         double-buffered K/V LDS, 1 barrier/tile, reg-prefetch (T14)
//   fc:   [8192,512] @ Wfc^T + bias -> fp32 out
// ws usage: 4 x 8 MiB bf16 buffers (Qp, Kp, Vt, Oattn) = 33.6 MB.

#define S_LEN 2048
#define EMB 512
#define NH 8
#define HD 64

typedef __bf16 bf16x8 __attribute__((ext_vector_type(8)));
typedef __bf16 bf16x4 __attribute__((ext_vector_type(4)));
typedef float f32x4 __attribute__((ext_vector_type(4)));

// XOR swizzle: permutes 16B slots within a 128B row -> conflict-free ds_read_b128
// for 16-lane column-slice reads. Applied identically on write+read.
__device__ __forceinline__ unsigned swz(unsigned byteoff, unsigned row) {
    return byteoff ^ ((row & 7u) << 4);
}

__global__ __launch_bounds__(256) void proj_kernel(
    const float* __restrict__ qin, const float* __restrict__ kin, const float* __restrict__ vin,
    const float* __restrict__ Wq, const float* __restrict__ Wk, const float* __restrict__ Wv,
    __bf16* __restrict__ Qp, __bf16* __restrict__ Kp, __bf16* __restrict__ Vt)
{
    __shared__ alignas(16) unsigned char xb[3][8192]; // 64x64 bf16 tiles (q,k,v rows), swizzled
    __shared__ alignas(16) unsigned char tb[8192];    // v-proj output tile for transpose, linear
    const int bh = blockIdx.y;
    const int b = bh >> 3, h = bh & 7;
    const int sblk = blockIdx.x << 6;
    const int tid = threadIdx.x;
    const int w = tid >> 6, l = tid & 63;
    const int col = l & 15, g = l >> 4;

    const float* srcs[3] = {qin, kin, vin};
    #pragma unroll
    for (int p = 0; p < 3; ++p) {
        const float* src = srcs[p] + ((size_t)b * S_LEN + sblk) * EMB + h * HD;
        #pragma unroll
        for (int it = 0; it < 4; ++it) {
            int c = tid + it * 256;            // 1024 float4 chunks = 64 rows x 16
            int row = c >> 4, c4 = c & 15;
            float4 f = *reinterpret_cast<const float4*>(src + (size_t)row * EMB + c4 * 4);
            bf16x4 t;
            t[0] = (__bf16)f.x; t[1] = (__bf16)f.y; t[2] = (__bf16)f.z; t[3] = (__bf16)f.w;
            *reinterpret_cast<bf16x4*>(&xb[p][swz(row * 128 + c4 * 8, row)]) = t;
        }
    }
    __syncthreads();

    const float* Ws[3] = {Wq, Wk, Wv};
    #pragma unroll
    for (int p = 0; p < 3; ++p) {
        // B-frags of W: lane holds W[e = 16*nf + col][k = ks*32 + 8*g .. +8]
        bf16x8 wf[4][2];
        #pragma unroll
        for (int nf = 0; nf < 4; ++nf)
            #pragma unroll
            for (int ks = 0; ks < 2; ++ks) {
                const float* base = Ws[p] + (nf * 16 + col) * HD + ks * 32 + g * 8;
                float4 f0 = *reinterpret_cast<const float4*>(base);
                float4 f1 = *reinterpret_cast<const float4*>(base + 4);
                bf16x8 r;
                r[0] = (__bf16)f0.x; r[1] = (__bf16)f0.y; r[2] = (__bf16)f0.z; r[3] = (__bf16)f0.w;
                r[4] = (__bf16)f1.x; r[5] = (__bf16)f1.y; r[6] = (__bf16)f1.z; r[7] = (__bf16)f1.w;
                wf[nf][ks] = r;
            }
        // A-frags: wave w owns s-rows w*16..w*16+15
        int arow = w * 16 + col;
        bf16x8 a0 = *reinterpret_cast<const bf16x8*>(&xb[p][swz(arow * 128 + g * 16, arow)]);
        bf16x8 a1 = *reinterpret_cast<const bf16x8*>(&xb[p][swz(arow * 128 + 64 + g * 16, arow)]);
        f32x4 acc[4];
        #pragma unroll
        for (int nf = 0; nf < 4; ++nf) acc[nf] = (f32x4){0.f, 0.f, 0.f, 0.f};
        #pragma unroll
        for (int nf = 0; nf < 4; ++nf) {
            acc[nf] = __builtin_amdgcn_mfma_f32_16x16x32_bf16(a0, wf[nf][0], acc[nf], 0, 0, 0);
            acc[nf] = __builtin_amdgcn_mfma_f32_16x16x32_bf16(a1, wf[nf][1], acc[nf], 0, 0, 0);
        }
        if (p < 2) {
            __bf16* dst = (p == 0 ? Qp : Kp);
            #pragma unroll
            for (int nf = 0; nf < 4; ++nf)
                #pragma unroll
                for (int r = 0; r < 4; ++r) {
                    int srow = sblk + w * 16 + g * 4 + r;
                    dst[((size_t)bh * S_LEN + srow) * HD + nf * 16 + col] = (__bf16)acc[nf][r];
                }
        } else {
            // v-proj -> LDS tile [s_local][e] for transposed global write
            #pragma unroll
            for (int nf = 0; nf < 4; ++nf)
                #pragma unroll
                for (int r = 0; r < 4; ++r) {
                    int srow = w * 16 + g * 4 + r;
                    *reinterpret_cast<__bf16*>(&tb[(srow * 64 + nf * 16 + col) * 2]) =
                        (__bf16)acc[nf][r];
                }
        }
    }
    __syncthreads();
    // transposed, coalesced write of Vt[bh][e][s]
    {
        int e = tid & 63, sc = tid >> 6;
        bf16x8 lo, hi;
        #pragma unroll
        for (int i = 0; i < 8; ++i)
            lo[i] = *reinterpret_cast<const __bf16*>(&tb[((sc * 16 + i) * 64 + e) * 2]);
        #pragma unroll
        for (int i = 0; i < 8; ++i)
            hi[i] = *reinterpret_cast<const __bf16*>(&tb[((sc * 16 + 8 + i) * 64 + e) * 2]);
        __bf16* dst = Vt + ((size_t)bh * HD + e) * S_LEN + sblk + sc * 16;
        *reinterpret_cast<bf16x8*>(dst) = lo;
        *reinterpret_cast<bf16x8*>(dst + 8) = hi;
    }
}

__global__ __launch_bounds__(256) void attn_kernel(
    const __bf16* __restrict__ Qp, const __bf16* __restrict__ Kp,
    const __bf16* __restrict__ Vt, __bf16* __restrict__ Oa)
{
    __shared__ alignas(16) unsigned char kb[2][8192];  // K tile [kv_row][d], swizzled, dbuf
    __shared__ alignas(16) unsigned char vb[2][8192];  // V tile [d][kv_row], swizzled, dbuf
    __shared__ alignas(16) unsigned char pb[4][2048];  // per-wave P tile [16][64], swizzled
    const int bh = blockIdx.y;
    const int b = bh >> 3, h = bh & 7;
    const int tid = threadIdx.x;
    const int w = tid >> 6, l = tid & 63;
    const int col = l & 15, g = l >> 4;
    const float K1 = 0.18033688011112042f; // log2(e)/8 : exp2 domain, 1/sqrt(d) folded

    const unsigned char* kgb =
        reinterpret_cast<const unsigned char*>(Kp + (size_t)bh * S_LEN * HD);
    const unsigned char* vgb =
        reinterpret_cast<const unsigned char*>(Vt + (size_t)bh * HD * S_LEN);
    // this thread's staging chunk coords (chunk c = tid + it*256; 512 x 16B per 8KB tile)
    const int srow0 = tid >> 3, so0 = (tid & 7) * 16;
    const int srow1 = (tid + 256) >> 3, so1 = ((tid + 256) & 7) * 16;

    #pragma unroll 1
    for (int pass = 0; pass < 2; ++pass) {
        // diagonal pairing: block x handles q-tiles x and 31-x -> 33 kv-tiles each
        const int qt = pass ? 31 - (int)blockIdx.x : (int)blockIdx.x;
        const int nt = qt + 1;

        // Q A-frags held in registers for this pass
        bf16x8 qf0, qf1;
        {
            const __bf16* qb = Qp + ((size_t)bh * S_LEN + qt * 64 + w * 16 + col) * HD + g * 8;
            qf0 = *reinterpret_cast<const bf16x8*>(qb);
            qf1 = *reinterpret_cast<const bf16x8*>(qb + 32);
        }
        f32x4 oacc[4];
        #pragma unroll
        for (int nf = 0; nf < 4; ++nf) oacc[nf] = (f32x4){0.f, 0.f, 0.f, 0.f};
        float m[4], lsum[4];
        #pragma unroll
        for (int r = 0; r < 4; ++r) { m[r] = -1e30f; lsum[r] = 0.f; }

        uint4 kr0, kr1, vr0, vr1;
        __syncthreads(); // prev pass's LDS reads complete before restage
        // prologue: stage tile 0 into buf 0
        kr0 = *reinterpret_cast<const uint4*>(kgb + tid * 16);
        kr1 = *reinterpret_cast<const uint4*>(kgb + (tid + 256) * 16);
        vr0 = *reinterpret_cast<const uint4*>(vgb + (size_t)srow0 * (S_LEN * 2) + so0);
        vr1 = *reinterpret_cast<const uint4*>(vgb + (size_t)srow1 * (S_LEN * 2) + so1);
        *reinterpret_cast<uint4*>(&kb[0][swz(srow0 * 128 + so0, srow0)]) = kr0;
        *reinterpret_cast<uint4*>(&kb[0][swz(srow1 * 128 + so1, srow1)]) = kr1;
        *reinterpret_cast<uint4*>(&vb[0][swz(srow0 * 128 + so0, srow0)]) = vr0;
        *reinterpret_cast<uint4*>(&vb[0][swz(srow1 * 128 + so1, srow1)]) = vr1;
        __syncthreads();

        int cur = 0;
        #pragma unroll 1
        for (int t = 0; t < nt; ++t) {
            const bool pf = (t + 1 < nt);
            if (pf) { // issue next tile's global loads early; latency hides under compute
                const unsigned char* kg = kgb + (size_t)(t + 1) * 8192;
                const unsigned char* vg = vgb + (size_t)(t + 1) * 128;
                kr0 = *reinterpret_cast<const uint4*>(kg + tid * 16);
                kr1 = *reinterpret_cast<const uint4*>(kg + (tid + 256) * 16);
                vr0 = *reinterpret_cast<const uint4*>(vg + (size_t)srow0 * (S_LEN * 2) + so0);
                vr1 = *reinterpret_cast<const uint4*>(vg + (size_t)srow1 * (S_LEN * 2) + so1);
            }
            // S = Q K^T (16 q-rows per wave x 64 kv-cols)
            f32x4 sf[4];
            #pragma unroll
            for (int nf = 0; nf < 4; ++nf) sf[nf] = (f32x4){0.f, 0.f, 0.f, 0.f};
            #pragma unroll
            for (int nf = 0; nf < 4; ++nf) {
                int krow = nf * 16 + col;
                bf16x8 kf0 = *reinterpret_cast<const bf16x8*>(
                    &kb[cur][swz(krow * 128 + g * 16, krow)]);
                bf16x8 kf1 = *reinterpret_cast<const bf16x8*>(
                    &kb[cur][swz(krow * 128 + 64 + g * 16, krow)]);
                sf[nf] = __builtin_amdgcn_mfma_f32_16x16x32_bf16(qf0, kf0, sf[nf], 0, 0, 0);
                sf[nf] = __builtin_amdgcn_mfma_f32_16x16x32_bf16(qf1, kf1, sf[nf], 0, 0, 0);
            }
            if (t == qt) { // diagonal tile: causal mask
                #pragma unroll
                for (int nf = 0; nf < 4; ++nf)
                    #pragma unroll
                    for (int r = 0; r < 4; ++r) {
                        int cg = nf * 16 + col;
                        int rg = w * 16 + g * 4 + r;
                        if (cg > rg) sf[nf][r] = -1e30f;
                    }
            }
            // online softmax; C/D layout: lane holds rows 4*g+r, col = 16*nf+col
            float rmax[4];
            #pragma unroll
            for (int r = 0; r < 4; ++r)
                rmax[r] = fmaxf(fmaxf(sf[0][r], sf[1][r]), fmaxf(sf[2][r], sf[3][r])) * K1;
            #pragma unroll
            for (int d = 1; d < 16; d <<= 1) {
                #pragma unroll
                for (int r = 0; r < 4; ++r) rmax[r] = fmaxf(rmax[r], __shfl_xor(rmax[r], d));
            }
            float sc[4], rsum[4];
            #pragma unroll
            for (int r = 0; r < 4; ++r) {
                float mn = fmaxf(m[r], rmax[r]);
                sc[r] = __builtin_exp2f(m[r] - mn);
                m[r] = mn;
                rsum[r] = 0.f;
            }
            #pragma unroll
            for (int nf = 0; nf < 4; ++nf) {
                #pragma unroll
                for (int r = 0; r < 4; ++r) {
                    float p = __builtin_exp2f(sf[nf][r] * K1 - m[r]);
                    rsum[r] += p;
                    int prow = g * 4 + r;
                    *reinterpret_cast<__bf16*>(
                        &pb[w][swz(prow * 128 + (nf * 16 + col) * 2, prow)]) = (__bf16)p;
                }
            }
            #pragma unroll
            for (int d = 1; d < 16; d <<= 1) {
                #pragma unroll
                for (int r = 0; r < 4; ++r) rsum[r] += __shfl_xor(rsum[r], d);
            }
            #pragma unroll
            for (int r = 0; r < 4; ++r) lsum[r] = lsum[r] * sc[r] + rsum[r];
            #pragma unroll
            for (int nf = 0; nf < 4; ++nf)
                #pragma unroll
                for (int r = 0; r < 4; ++r) oacc[nf][r] *= sc[r];
            // O += P V (pb[w] is wave-private: no barrier, compiler lgkmcnt orders it)
            bf16x8 pf0 = *reinterpret_cast<const bf16x8*>(&pb[w][swz(col * 128 + g * 16, col)]);
            bf16x8 pf1 = *reinterpret_cast<const bf16x8*>(
                &pb[w][swz(col * 128 + 64 + g * 16, col)]);
            #pragma unroll
            for (int nf = 0; nf < 4; ++nf) {
                int vrow = nf * 16 + col;
                bf16x8 vf0 = *reinterpret_cast<const bf16x8*>(
                    &vb[cur][swz(vrow * 128 + g * 16, vrow)]);
                bf16x8 vf1 = *reinterpret_cast<const bf16x8*>(
                    &vb[cur][swz(vrow * 128 + 64 + g * 16, vrow)]);
                oacc[nf] = __builtin_amdgcn_mfma_f32_16x16x32_bf16(pf0, vf0, oacc[nf], 0, 0, 0);
                oacc[nf] = __builtin_amdgcn_mfma_f32_16x16x32_bf16(pf1, vf1, oacc[nf], 0, 0, 0);
            }
            if (pf) { // write prefetched tile into the other buffer
                *reinterpret_cast<uint4*>(&kb[cur ^ 1][swz(srow0 * 128 + so0, srow0)]) = kr0;
                *reinterpret_cast<uint4*>(&kb[cur ^ 1][swz(srow1 * 128 + so1, srow1)]) = kr1;
                *reinterpret_cast<uint4*>(&vb[cur ^ 1][swz(srow0 * 128 + so0, srow0)]) = vr0;
                *reinterpret_cast<uint4*>(&vb[cur ^ 1][swz(srow1 * 128 + so1, srow1)]) = vr1;
            }
            __syncthreads(); // single barrier per tile
            cur ^= 1;
        }
        #pragma unroll
        for (int r = 0; r < 4; ++r) lsum[r] = 1.0f / lsum[r];
        #pragma unroll
        for (int nf = 0; nf < 4; ++nf)
            #pragma unroll
            for (int r = 0; r < 4; ++r) {
                int s = qt * 64 + w * 16 + g * 4 + r;
                Oa[((size_t)b * S_LEN + s) * EMB + h * HD + nf * 16 + col] =
                    (__bf16)(oacc[nf][r] * lsum[r]);
            }
    }
}

__global__ __launch_bounds__(256) void fc_kernel(
    const __bf16* __restrict__ A,   // Oattn [B*S][E] bf16
    const float* __restrict__ Wfc,  // [E][E] fp32, row-major (n, k)
    const float* __restrict__ bfc,  // [E]
    float* __restrict__ out)        // [B*S][E] fp32
{
    __shared__ alignas(16) unsigned char ab[8192]; // A tile 64x64 bf16, swizzled
    __shared__ alignas(16) unsigned char bb[8192]; // W tile 64x64 bf16, swizzled
    const int r0 = blockIdx.x << 6;
    const int n0 = blockIdx.y << 6;
    const int tid = threadIdx.x;
    const int w = tid >> 6, l = tid & 63;
    const int col = l & 15, g = l >> 4;

    f32x4 acc[4];
    #pragma unroll
    for (int nf = 0; nf < 4; ++nf) acc[nf] = (f32x4){0.f, 0.f, 0.f, 0.f};

    for (int kc = 0; kc < 8; ++kc) {
        __syncthreads();
        #pragma unroll
        for (int it = 0; it < 2; ++it) { // A tile: 512 uint4 chunks
            int c = tid + it * 256;
            int row = c >> 3, o = (c & 7) * 16;
            uint4 d = *reinterpret_cast<const uint4*>(
                reinterpret_cast<const unsigned char*>(A) +
                ((size_t)(r0 + row) * EMB + kc * 64) * 2 + o);
            *reinterpret_cast<uint4*>(&ab[swz(row * 128 + o, row)]) = d;
        }
        #pragma unroll
        for (int it = 0; it < 4; ++it) { // W tile: 1024 float4 chunks, cvt to bf16
            int c = tid + it * 256;
            int row = c >> 4, c4 = c & 15;
            float4 f = *reinterpret_cast<const float4*>(
                Wfc + (size_t)(n0 + row) * EMB + kc * 64 + c4 * 4);
            bf16x4 t;
            t[0] = (__bf16)f.x; t[1] = (__bf16)f.y; t[2] = (__bf16)f.z; t[3] = (__bf16)f.w;
            *reinterpret_cast<bf16x4*>(&bb[swz(row * 128 + c4 * 8, row)]) = t;
        }
        __syncthreads();
        int arow = w * 16 + col;
        #pragma unroll
        for (int ks = 0; ks < 2; ++ks) {
            bf16x8 af = *reinterpret_cast<const bf16x8*>(
                &ab[swz(arow * 128 + ks * 64 + g * 16, arow)]);
            #pragma unroll
            for (int nf = 0; nf < 4; ++nf) {
                int brow = nf * 16 + col;
                bf16x8 bf = *reinterpret_cast<const bf16x8*>(
                    &bb[swz(brow * 128 + ks * 64 + g * 16, brow)]);
                acc[nf] = __builtin_amdgcn_mfma_f32_16x16x32_bf16(af, bf, acc[nf], 0, 0, 0);
            }
        }
    }
    #pragma unroll
    for (int nf = 0; nf < 4; ++nf) {
        float bias = bfc[n0 + nf * 16 + col];
        #pragma unroll
        for (int r = 0; r < 4; ++r) {
            int row = r0 + w * 16 + g * 4 + r;
            out[(size_t)row * EMB + n0 + nf * 16 + col] = acc[nf][r] + bias;
        }
    }
}

extern "C" void kernel_launch(void* const* d_in, const int* in_sizes, int n_in,
                              void* d_out, int out_size, void* d_ws, size_t ws_size,
                              hipStream_t stream) {
    const float* q   = (const float*)d_in[0];
    const float* k   = (const float*)d_in[1];
    const float* v   = (const float*)d_in[2];
    const float* Wq  = (const float*)d_in[3];
    const float* Wk  = (const float*)d_in[4];
    const float* Wv  = (const float*)d_in[5];
    const float* Wfc = (const float*)d_in[6];
    const float* bfc = (const float*)d_in[7];
    // d_in[8] = mask: causal tril, hardcoded in attn_kernel.
    float* out = (float*)d_out;

    char* ws = (char*)d_ws;
    const size_t SZ = (size_t)4 * NH * S_LEN * HD * sizeof(__bf16); // 8 MiB
    __bf16* Qp = (__bf16*)(ws);
    __bf16* Kp = (__bf16*)(ws + SZ);
    __bf16* Vt = (__bf16*)(ws + 2 * SZ);
    __bf16* Oa = (__bf16*)(ws + 3 * SZ);

    proj_kernel<<<dim3(S_LEN / 64, 4 * NH), 256, 0, stream>>>(q, k, v, Wq, Wk, Wv, Qp, Kp, Vt);
    attn_kernel<<<dim3(16, 4 * NH), 256, 0, stream>>>(Qp, Kp, Vt, Oa);
    fc_kernel<<<dim3((4 * S_LEN) / 64, EMB / 64), 256, 0, stream>>>(Oa, Wfc, bfc, out);
}

// Round 4
// 114.126 us; speedup vs baseline: 1.9516x; 1.1645x over previous
//
#include <hip/hip_runtime.h>
#include <hip/hip_bf16.h>

// MultiHeadAttention B=4 S=2048 E=512 H=8 D=64, causal. Inputs fp32, output fp32.
// 3-kernel bf16-MFMA pipeline:
//   proj: X @ W^T per head (shared W), writes Qp/Kp [bh][s][d] and Vt [bh][d][s]
//   attn: flash attention, 1024 blocks LPT-ordered (longest q-tile first), XCD-affine
//         bh mapping, double-buffered K/V LDS, 1 barrier/tile, reg-prefetch,
//         deferred cross-lane rsum reduction
//   fc:   [8192,512] @ Wfc^T + bias -> fp32 out
// ws usage: 4 x 8 MiB bf16 buffers (Qp, Kp, Vt, Oattn) = 33.6 MB.

#define S_LEN 2048
#define EMB 512
#define NH 8
#define HD 64

typedef __bf16 bf16x8 __attribute__((ext_vector_type(8)));
typedef __bf16 bf16x4 __attribute__((ext_vector_type(4)));
typedef float f32x4 __attribute__((ext_vector_type(4)));

// XOR swizzle: permutes 16B slots within a 128B row -> conflict-free ds_read_b128
// for 16-lane column-slice reads. Applied identically on write+read.
__device__ __forceinline__ unsigned swz(unsigned byteoff, unsigned row) {
    return byteoff ^ ((row & 7u) << 4);
}

__global__ __launch_bounds__(256) void proj_kernel(
    const float* __restrict__ qin, const float* __restrict__ kin, const float* __restrict__ vin,
    const float* __restrict__ Wq, const float* __restrict__ Wk, const float* __restrict__ Wv,
    __bf16* __restrict__ Qp, __bf16* __restrict__ Kp, __bf16* __restrict__ Vt)
{
    __shared__ alignas(16) unsigned char xb[3][8192]; // 64x64 bf16 tiles (q,k,v rows), swizzled
    __shared__ alignas(16) unsigned char tb[8192];    // v-proj output tile for transpose, linear
    const int bh = blockIdx.y;
    const int b = bh >> 3, h = bh & 7;
    const int sblk = blockIdx.x << 6;
    const int tid = threadIdx.x;
    const int w = tid >> 6, l = tid & 63;
    const int col = l & 15, g = l >> 4;

    const float* srcs[3] = {qin, kin, vin};
    #pragma unroll
    for (int p = 0; p < 3; ++p) {
        const float* src = srcs[p] + ((size_t)b * S_LEN + sblk) * EMB + h * HD;
        #pragma unroll
        for (int it = 0; it < 4; ++it) {
            int c = tid + it * 256;            // 1024 float4 chunks = 64 rows x 16
            int row = c >> 4, c4 = c & 15;
            float4 f = *reinterpret_cast<const float4*>(src + (size_t)row * EMB + c4 * 4);
            bf16x4 t;
            t[0] = (__bf16)f.x; t[1] = (__bf16)f.y; t[2] = (__bf16)f.z; t[3] = (__bf16)f.w;
            *reinterpret_cast<bf16x4*>(&xb[p][swz(row * 128 + c4 * 8, row)]) = t;
        }
    }
    __syncthreads();

    const float* Ws[3] = {Wq, Wk, Wv};
    #pragma unroll
    for (int p = 0; p < 3; ++p) {
        // B-frags of W: lane holds W[e = 16*nf + col][k = ks*32 + 8*g .. +8]
        bf16x8 wf[4][2];
        #pragma unroll
        for (int nf = 0; nf < 4; ++nf)
            #pragma unroll
            for (int ks = 0; ks < 2; ++ks) {
                const float* base = Ws[p] + (nf * 16 + col) * HD + ks * 32 + g * 8;
                float4 f0 = *reinterpret_cast<const float4*>(base);
                float4 f1 = *reinterpret_cast<const float4*>(base + 4);
                bf16x8 r;
                r[0] = (__bf16)f0.x; r[1] = (__bf16)f0.y; r[2] = (__bf16)f0.z; r[3] = (__bf16)f0.w;
                r[4] = (__bf16)f1.x; r[5] = (__bf16)f1.y; r[6] = (__bf16)f1.z; r[7] = (__bf16)f1.w;
                wf[nf][ks] = r;
            }
        // A-frags: wave w owns s-rows w*16..w*16+15
        int arow = w * 16 + col;
        bf16x8 a0 = *reinterpret_cast<const bf16x8*>(&xb[p][swz(arow * 128 + g * 16, arow)]);
        bf16x8 a1 = *reinterpret_cast<const bf16x8*>(&xb[p][swz(arow * 128 + 64 + g * 16, arow)]);
        f32x4 acc[4];
        #pragma unroll
        for (int nf = 0; nf < 4; ++nf) acc[nf] = (f32x4){0.f, 0.f, 0.f, 0.f};
        #pragma unroll
        for (int nf = 0; nf < 4; ++nf) {
            acc[nf] = __builtin_amdgcn_mfma_f32_16x16x32_bf16(a0, wf[nf][0], acc[nf], 0, 0, 0);
            acc[nf] = __builtin_amdgcn_mfma_f32_16x16x32_bf16(a1, wf[nf][1], acc[nf], 0, 0, 0);
        }
        if (p < 2) {
            __bf16* dst = (p == 0 ? Qp : Kp);
            #pragma unroll
            for (int nf = 0; nf < 4; ++nf)
                #pragma unroll
                for (int r = 0; r < 4; ++r) {
                    int srow = sblk + w * 16 + g * 4 + r;
                    dst[((size_t)bh * S_LEN + srow) * HD + nf * 16 + col] = (__bf16)acc[nf][r];
                }
        } else {
            // v-proj -> LDS tile [s_local][e] for transposed global write
            #pragma unroll
            for (int nf = 0; nf < 4; ++nf)
                #pragma unroll
                for (int r = 0; r < 4; ++r) {
                    int srow = w * 16 + g * 4 + r;
                    *reinterpret_cast<__bf16*>(&tb[(srow * 64 + nf * 16 + col) * 2]) =
                        (__bf16)acc[nf][r];
                }
        }
    }
    __syncthreads();
    // transposed, coalesced write of Vt[bh][e][s]
    {
        int e = tid & 63, sc = tid >> 6;
        bf16x8 lo, hi;
        #pragma unroll
        for (int i = 0; i < 8; ++i)
            lo[i] = *reinterpret_cast<const __bf16*>(&tb[((sc * 16 + i) * 64 + e) * 2]);
        #pragma unroll
        for (int i = 0; i < 8; ++i)
            hi[i] = *reinterpret_cast<const __bf16*>(&tb[((sc * 16 + 8 + i) * 64 + e) * 2]);
        __bf16* dst = Vt + ((size_t)bh * HD + e) * S_LEN + sblk + sc * 16;
        *reinterpret_cast<bf16x8*>(dst) = lo;
        *reinterpret_cast<bf16x8*>(dst + 8) = hi;
    }
}

__global__ __launch_bounds__(256) void attn_kernel(
    const __bf16* __restrict__ Qp, const __bf16* __restrict__ Kp,
    const __bf16* __restrict__ Vt, __bf16* __restrict__ Oa)
{
    __shared__ alignas(16) unsigned char kb[2][8192];  // K tile [kv_row][d], swizzled, dbuf
    __shared__ alignas(16) unsigned char vb[2][8192];  // V tile [d][kv_row], swizzled, dbuf
    __shared__ alignas(16) unsigned char pb[4][2048];  // per-wave P tile [16][64], swizzled
    // LPT + XCD affinity: same-bh blocks share l%8 (same XCD under round-robin
    // dispatch, K/V L2-resident); qt = 31 - (l>>5): longest blocks dispatch first.
    const int l_id = blockIdx.x;
    const int bh = l_id & 31;
    const int qt = 31 - (l_id >> 5);
    const int b = bh >> 3, h = bh & 7;
    const int tid = threadIdx.x;
    const int w = tid >> 6, l = tid & 63;
    const int col = l & 15, g = l >> 4;
    const float K1 = 0.18033688011112042f; // log2(e)/8 : exp2 domain, 1/sqrt(d) folded

    const unsigned char* kgb =
        reinterpret_cast<const unsigned char*>(Kp + (size_t)bh * S_LEN * HD);
    const unsigned char* vgb =
        reinterpret_cast<const unsigned char*>(Vt + (size_t)bh * HD * S_LEN);
    // this thread's staging chunk coords (chunk c = tid + it*256; 512 x 16B per 8KB tile)
    const int srow0 = tid >> 3, so0 = (tid & 7) * 16;
    const int srow1 = (tid + 256) >> 3, so1 = ((tid + 256) & 7) * 16;

    const int nt = qt + 1;

    // Q A-frags held in registers
    bf16x8 qf0, qf1;
    {
        const __bf16* qb = Qp + ((size_t)bh * S_LEN + qt * 64 + w * 16 + col) * HD + g * 8;
        qf0 = *reinterpret_cast<const bf16x8*>(qb);
        qf1 = *reinterpret_cast<const bf16x8*>(qb + 32);
    }
    f32x4 oacc[4];
    #pragma unroll
    for (int nf = 0; nf < 4; ++nf) oacc[nf] = (f32x4){0.f, 0.f, 0.f, 0.f};
    float m[4], lsum[4]; // lsum = PER-LANE partial row sum (cross-lane reduce deferred)
    #pragma unroll
    for (int r = 0; r < 4; ++r) { m[r] = -1e30f; lsum[r] = 0.f; }

    uint4 kr0, kr1, vr0, vr1;
    // prologue: stage tile 0 into buf 0
    kr0 = *reinterpret_cast<const uint4*>(kgb + tid * 16);
    kr1 = *reinterpret_cast<const uint4*>(kgb + (tid + 256) * 16);
    vr0 = *reinterpret_cast<const uint4*>(vgb + (size_t)srow0 * (S_LEN * 2) + so0);
    vr1 = *reinterpret_cast<const uint4*>(vgb + (size_t)srow1 * (S_LEN * 2) + so1);
    *reinterpret_cast<uint4*>(&kb[0][swz(srow0 * 128 + so0, srow0)]) = kr0;
    *reinterpret_cast<uint4*>(&kb[0][swz(srow1 * 128 + so1, srow1)]) = kr1;
    *reinterpret_cast<uint4*>(&vb[0][swz(srow0 * 128 + so0, srow0)]) = vr0;
    *reinterpret_cast<uint4*>(&vb[0][swz(srow1 * 128 + so1, srow1)]) = vr1;
    __syncthreads();

    int cur = 0;
    #pragma unroll 1
    for (int t = 0; t < nt; ++t) {
        const bool pf = (t + 1 < nt);
        if (pf) { // issue next tile's global loads early; latency hides under compute
            const unsigned char* kg = kgb + (size_t)(t + 1) * 8192;
            const unsigned char* vg = vgb + (size_t)(t + 1) * 128;
            kr0 = *reinterpret_cast<const uint4*>(kg + tid * 16);
            kr1 = *reinterpret_cast<const uint4*>(kg + (tid + 256) * 16);
            vr0 = *reinterpret_cast<const uint4*>(vg + (size_t)srow0 * (S_LEN * 2) + so0);
            vr1 = *reinterpret_cast<const uint4*>(vg + (size_t)srow1 * (S_LEN * 2) + so1);
        }
        // S = Q K^T (16 q-rows per wave x 64 kv-cols)
        f32x4 sf[4];
        #pragma unroll
        for (int nf = 0; nf < 4; ++nf) sf[nf] = (f32x4){0.f, 0.f, 0.f, 0.f};
        #pragma unroll
        for (int nf = 0; nf < 4; ++nf) {
            int krow = nf * 16 + col;
            bf16x8 kf0 = *reinterpret_cast<const bf16x8*>(
                &kb[cur][swz(krow * 128 + g * 16, krow)]);
            bf16x8 kf1 = *reinterpret_cast<const bf16x8*>(
                &kb[cur][swz(krow * 128 + 64 + g * 16, krow)]);
            sf[nf] = __builtin_amdgcn_mfma_f32_16x16x32_bf16(qf0, kf0, sf[nf], 0, 0, 0);
            sf[nf] = __builtin_amdgcn_mfma_f32_16x16x32_bf16(qf1, kf1, sf[nf], 0, 0, 0);
        }
        if (t == qt) { // diagonal tile: causal mask
            #pragma unroll
            for (int nf = 0; nf < 4; ++nf)
                #pragma unroll
                for (int r = 0; r < 4; ++r) {
                    int cg = nf * 16 + col;
                    int rg = w * 16 + g * 4 + r;
                    if (cg > rg) sf[nf][r] = -1e30f;
                }
        }
        // online softmax; C/D layout: lane holds rows 4*g+r, col = 16*nf+col
        float rmax[4];
        #pragma unroll
        for (int r = 0; r < 4; ++r)
            rmax[r] = fmaxf(fmaxf(sf[0][r], sf[1][r]), fmaxf(sf[2][r], sf[3][r])) * K1;
        #pragma unroll
        for (int d = 1; d < 16; d <<= 1) {
            #pragma unroll
            for (int r = 0; r < 4; ++r) rmax[r] = fmaxf(rmax[r], __shfl_xor(rmax[r], d));
        }
        float sc[4], rsum[4];
        #pragma unroll
        for (int r = 0; r < 4; ++r) {
            float mn = fmaxf(m[r], rmax[r]);
            sc[r] = __builtin_exp2f(m[r] - mn);
            m[r] = mn;
            rsum[r] = 0.f;
        }
        #pragma unroll
        for (int nf = 0; nf < 4; ++nf) {
            #pragma unroll
            for (int r = 0; r < 4; ++r) {
                float p = __builtin_exp2f(sf[nf][r] * K1 - m[r]);
                rsum[r] += p;
                int prow = g * 4 + r;
                *reinterpret_cast<__bf16*>(
                    &pb[w][swz(prow * 128 + (nf * 16 + col) * 2, prow)]) = (__bf16)p;
            }
        }
        // deferred: lsum stays a per-lane partial; sc is uniform across the row group
        #pragma unroll
        for (int r = 0; r < 4; ++r) lsum[r] = lsum[r] * sc[r] + rsum[r];
        #pragma unroll
        for (int nf = 0; nf < 4; ++nf)
            #pragma unroll
            for (int r = 0; r < 4; ++r) oacc[nf][r] *= sc[r];
        // O += P V (pb[w] is wave-private: no barrier, compiler lgkmcnt orders it)
        bf16x8 pf0 = *reinterpret_cast<const bf16x8*>(&pb[w][swz(col * 128 + g * 16, col)]);
        bf16x8 pf1 = *reinterpret_cast<const bf16x8*>(
            &pb[w][swz(col * 128 + 64 + g * 16, col)]);
        #pragma unroll
        for (int nf = 0; nf < 4; ++nf) {
            int vrow = nf * 16 + col;
            bf16x8 vf0 = *reinterpret_cast<const bf16x8*>(
                &vb[cur][swz(vrow * 128 + g * 16, vrow)]);
            bf16x8 vf1 = *reinterpret_cast<const bf16x8*>(
                &vb[cur][swz(vrow * 128 + 64 + g * 16, vrow)]);
            oacc[nf] = __builtin_amdgcn_mfma_f32_16x16x32_bf16(pf0, vf0, oacc[nf], 0, 0, 0);
            oacc[nf] = __builtin_amdgcn_mfma_f32_16x16x32_bf16(pf1, vf1, oacc[nf], 0, 0, 0);
        }
        if (pf) { // write prefetched tile into the other buffer
            *reinterpret_cast<uint4*>(&kb[cur ^ 1][swz(srow0 * 128 + so0, srow0)]) = kr0;
            *reinterpret_cast<uint4*>(&kb[cur ^ 1][swz(srow1 * 128 + so1, srow1)]) = kr1;
            *reinterpret_cast<uint4*>(&vb[cur ^ 1][swz(srow0 * 128 + so0, srow0)]) = vr0;
            *reinterpret_cast<uint4*>(&vb[cur ^ 1][swz(srow1 * 128 + so1, srow1)]) = vr1;
        }
        __syncthreads(); // single barrier per tile
        cur ^= 1;
    }
    // final cross-lane lsum reduction (deferred from the loop): sum over the 16
    // col-lanes of each row group
    #pragma unroll
    for (int d = 1; d < 16; d <<= 1) {
        #pragma unroll
        for (int r = 0; r < 4; ++r) lsum[r] += __shfl_xor(lsum[r], d);
    }
    #pragma unroll
    for (int r = 0; r < 4; ++r) lsum[r] = 1.0f / lsum[r];
    #pragma unroll
    for (int nf = 0; nf < 4; ++nf)
        #pragma unroll
        for (int r = 0; r < 4; ++r) {
            int s = qt * 64 + w * 16 + g * 4 + r;
            Oa[((size_t)b * S_LEN + s) * EMB + h * HD + nf * 16 + col] =
                (__bf16)(oacc[nf][r] * lsum[r]);
        }
}

__global__ __launch_bounds__(256) void fc_kernel(
    const __bf16* __restrict__ A,   // Oattn [B*S][E] bf16
    const float* __restrict__ Wfc,  // [E][E] fp32, row-major (n, k)
    const float* __restrict__ bfc,  // [E]
    float* __restrict__ out)        // [B*S][E] fp32
{
    __shared__ alignas(16) unsigned char ab[8192]; // A tile 64x64 bf16, swizzled
    __shared__ alignas(16) unsigned char bb[8192]; // W tile 64x64 bf16, swizzled
    const int r0 = blockIdx.x << 6;
    const int n0 = blockIdx.y << 6;
    const int tid = threadIdx.x;
    const int w = tid >> 6, l = tid & 63;
    const int col = l & 15, g = l >> 4;

    f32x4 acc[4];
    #pragma unroll
    for (int nf = 0; nf < 4; ++nf) acc[nf] = (f32x4){0.f, 0.f, 0.f, 0.f};

    for (int kc = 0; kc < 8; ++kc) {
        __syncthreads();
        #pragma unroll
        for (int it = 0; it < 2; ++it) { // A tile: 512 uint4 chunks
            int c = tid + it * 256;
            int row = c >> 3, o = (c & 7) * 16;
            uint4 d = *reinterpret_cast<const uint4*>(
                reinterpret_cast<const unsigned char*>(A) +
                ((size_t)(r0 + row) * EMB + kc * 64) * 2 + o);
            *reinterpret_cast<uint4*>(&ab[swz(row * 128 + o, row)]) = d;
        }
        #pragma unroll
        for (int it = 0; it < 4; ++it) { // W tile: 1024 float4 chunks, cvt to bf16
            int c = tid + it * 256;
            int row = c >> 4, c4 = c & 15;
            float4 f = *reinterpret_cast<const float4*>(
                Wfc + (size_t)(n0 + row) * EMB + kc * 64 + c4 * 4);
            bf16x4 t;
            t[0] = (__bf16)f.x; t[1] = (__bf16)f.y; t[2] = (__bf16)f.z; t[3] = (__bf16)f.w;
            *reinterpret_cast<bf16x4*>(&bb[swz(row * 128 + c4 * 8, row)]) = t;
        }
        __syncthreads();
        int arow = w * 16 + col;
        #pragma unroll
        for (int ks = 0; ks < 2; ++ks) {
            bf16x8 af = *reinterpret_cast<const bf16x8*>(
                &ab[swz(arow * 128 + ks * 64 + g * 16, arow)]);
            #pragma unroll
            for (int nf = 0; nf < 4; ++nf) {
                int brow = nf * 16 + col;
                bf16x8 bf = *reinterpret_cast<const bf16x8*>(
                    &bb[swz(brow * 128 + ks * 64 + g * 16, brow)]);
                acc[nf] = __builtin_amdgcn_mfma_f32_16x16x32_bf16(af, bf, acc[nf], 0, 0, 0);
            }
        }
    }
    #pragma unroll
    for (int nf = 0; nf < 4; ++nf) {
        float bias = bfc[n0 + nf * 16 + col];
        #pragma unroll
        for (int r = 0; r < 4; ++r) {
            int row = r0 + w * 16 + g * 4 + r;
            out[(size_t)row * EMB + n0 + nf * 16 + col] = acc[nf][r] + bias;
        }
    }
}

extern "C" void kernel_launch(void* const* d_in, const int* in_sizes, int n_in,
                              void* d_out, int out_size, void* d_ws, size_t ws_size,
                              hipStream_t stream) {
    const float* q   = (const float*)d_in[0];
    const float* k   = (const float*)d_in[1];
    const float* v   = (const float*)d_in[2];
    const float* Wq  = (const float*)d_in[3];
    const float* Wk  = (const float*)d_in[4];
    const float* Wv  = (const float*)d_in[5];
    const float* Wfc = (const float*)d_in[6];
    const float* bfc = (const float*)d_in[7];
    // d_in[8] = mask: causal tril, hardcoded in attn_kernel.
    float* out = (float*)d_out;

    char* ws = (char*)d_ws;
    const size_t SZ = (size_t)4 * NH * S_LEN * HD * sizeof(__bf16); // 8 MiB
    __bf16* Qp = (__bf16*)(ws);
    __bf16* Kp = (__bf16*)(ws + SZ);
    __bf16* Vt = (__bf16*)(ws + 2 * SZ);
    __bf16* Oa = (__bf16*)(ws + 3 * SZ);

    proj_kernel<<<dim3(S_LEN / 64, 4 * NH), 256, 0, stream>>>(q, k, v, Wq, Wk, Wv, Qp, Kp, Vt);
    attn_kernel<<<dim3(32 * 32), 256, 0, stream>>>(Qp, Kp, Vt, Oa);
    fc_kernel<<<dim3((4 * S_LEN) / 64, EMB / 64), 256, 0, stream>>>(Oa, Wfc, bfc, out);
}

// Round 6
// 107.873 us; speedup vs baseline: 2.0648x; 1.0580x over previous
//
#include <hip/hip_runtime.h>
#include <hip/hip_bf16.h>

// MultiHeadAttention B=4 S=2048 E=512 H=8 D=64, causal. Inputs fp32, output fp32.
// 3-kernel bf16-MFMA pipeline:
//   proj: X @ W^T per head; Qp pre-scaled by log2(e)/8; Qp/Kp [bh][s][d], Vt [bh][d][s]
//   attn: flash attention in TRANSPOSED space (T12): S^T=mfma(K,Q), O^T=mfma(V^T,P^T);
//         P^T built in-register via cvt_pk_bf16 + DOUBLE ds_bpermute + cndmask;
//         LPT grid + XCD-affine bh, dbuf K/V LDS, 1 barrier/tile, reg-prefetch
//   fc:   [8192,512] @ Wfc^T + bias -> fp32 out
#define S_LEN 2048
#define EMB 512
#define NH 8
#define HD 64

typedef __bf16 bf16x8 __attribute__((ext_vector_type(8)));
typedef __bf16 bf16x4 __attribute__((ext_vector_type(4)));
typedef float f32x4 __attribute__((ext_vector_type(4)));
typedef int i32x4 __attribute__((ext_vector_type(4)));

__device__ __forceinline__ unsigned swz(unsigned byteoff, unsigned row) {
    return byteoff ^ ((row & 7u) << 4);
}

__global__ __launch_bounds__(256) void proj_kernel(
    const float* __restrict__ qin, const float* __restrict__ kin, const float* __restrict__ vin,
    const float* __restrict__ Wq, const float* __restrict__ Wk, const float* __restrict__ Wv,
    __bf16* __restrict__ Qp, __bf16* __restrict__ Kp, __bf16* __restrict__ Vt)
{
    __shared__ alignas(16) unsigned char xb[3][8192]; // 64x64 bf16 tiles (q,k,v rows), swizzled
    __shared__ alignas(16) unsigned char tb[8192];    // v-proj output tile for transpose, linear
    const int bh = blockIdx.y;
    const int b = bh >> 3, h = bh & 7;
    const int sblk = blockIdx.x << 6;
    const int tid = threadIdx.x;
    const int w = tid >> 6, l = tid & 63;
    const int col = l & 15, g = l >> 4;
    const float K1 = 0.18033688011112042f; // log2(e)/8 folded into Qp

    const float* srcs[3] = {qin, kin, vin};
    #pragma unroll
    for (int p = 0; p < 3; ++p) {
        const float* src = srcs[p] + ((size_t)b * S_LEN + sblk) * EMB + h * HD;
        #pragma unroll
        for (int it = 0; it < 4; ++it) {
            int c = tid + it * 256;            // 1024 float4 chunks = 64 rows x 16
            int row = c >> 4, c4 = c & 15;
            float4 f = *reinterpret_cast<const float4*>(src + (size_t)row * EMB + c4 * 4);
            bf16x4 t;
            t[0] = (__bf16)f.x; t[1] = (__bf16)f.y; t[2] = (__bf16)f.z; t[3] = (__bf16)f.w;
            *reinterpret_cast<bf16x4*>(&xb[p][swz(row * 128 + c4 * 8, row)]) = t;
        }
    }
    __syncthreads();

    const float* Ws[3] = {Wq, Wk, Wv};
    #pragma unroll
    for (int p = 0; p < 3; ++p) {
        bf16x8 wf[4][2];
        #pragma unroll
        for (int nf = 0; nf < 4; ++nf)
            #pragma unroll
            for (int ks = 0; ks < 2; ++ks) {
                const float* base = Ws[p] + (nf * 16 + col) * HD + ks * 32 + g * 8;
                float4 f0 = *reinterpret_cast<const float4*>(base);
                float4 f1 = *reinterpret_cast<const float4*>(base + 4);
                bf16x8 r;
                r[0] = (__bf16)f0.x; r[1] = (__bf16)f0.y; r[2] = (__bf16)f0.z; r[3] = (__bf16)f0.w;
                r[4] = (__bf16)f1.x; r[5] = (__bf16)f1.y; r[6] = (__bf16)f1.z; r[7] = (__bf16)f1.w;
                wf[nf][ks] = r;
            }
        int arow = w * 16 + col;
        bf16x8 a0 = *reinterpret_cast<const bf16x8*>(&xb[p][swz(arow * 128 + g * 16, arow)]);
        bf16x8 a1 = *reinterpret_cast<const bf16x8*>(&xb[p][swz(arow * 128 + 64 + g * 16, arow)]);
        f32x4 acc[4];
        #pragma unroll
        for (int nf = 0; nf < 4; ++nf) acc[nf] = (f32x4){0.f, 0.f, 0.f, 0.f};
        #pragma unroll
        for (int nf = 0; nf < 4; ++nf) {
            acc[nf] = __builtin_amdgcn_mfma_f32_16x16x32_bf16(a0, wf[nf][0], acc[nf], 0, 0, 0);
            acc[nf] = __builtin_amdgcn_mfma_f32_16x16x32_bf16(a1, wf[nf][1], acc[nf], 0, 0, 0);
        }
        if (p < 2) {
            __bf16* dst = (p == 0 ? Qp : Kp);
            const float s0 = (p == 0) ? K1 : 1.0f; // fold softmax scale into Q
            #pragma unroll
            for (int nf = 0; nf < 4; ++nf)
                #pragma unroll
                for (int r = 0; r < 4; ++r) {
                    int srow = sblk + w * 16 + g * 4 + r;
                    dst[((size_t)bh * S_LEN + srow) * HD + nf * 16 + col] =
                        (__bf16)(acc[nf][r] * s0);
                }
        } else {
            #pragma unroll
            for (int nf = 0; nf < 4; ++nf)
                #pragma unroll
                for (int r = 0; r < 4; ++r) {
                    int srow = w * 16 + g * 4 + r;
                    *reinterpret_cast<__bf16*>(&tb[(srow * 64 + nf * 16 + col) * 2]) =
                        (__bf16)acc[nf][r];
                }
        }
    }
    __syncthreads();
    {
        int e = tid & 63, sc = tid >> 6;
        bf16x8 lo, hi;
        #pragma unroll
        for (int i = 0; i < 8; ++i)
            lo[i] = *reinterpret_cast<const __bf16*>(&tb[((sc * 16 + i) * 64 + e) * 2]);
        #pragma unroll
        for (int i = 0; i < 8; ++i)
            hi[i] = *reinterpret_cast<const __bf16*>(&tb[((sc * 16 + 8 + i) * 64 + e) * 2]);
        __bf16* dst = Vt + ((size_t)bh * HD + e) * S_LEN + sblk + sc * 16;
        *reinterpret_cast<bf16x8*>(dst) = lo;
        *reinterpret_cast<bf16x8*>(dst + 8) = hi;
    }
}

__global__ __launch_bounds__(256) void attn_kernel(
    const __bf16* __restrict__ Qp, const __bf16* __restrict__ Kp,
    const __bf16* __restrict__ Vt, __bf16* __restrict__ Oa)
{
    __shared__ alignas(16) unsigned char kb[2][8192];  // K tile [kv][d], swizzled, dbuf
    __shared__ alignas(16) unsigned char vb[2][8192];  // V^T tile [d][kv], swizzled, dbuf
    const int l_id = blockIdx.x;
    const int bh = l_id & 31;            // XCD-affine: same-bh blocks share l%8
    const int qt = 31 - (l_id >> 5);     // LPT: longest blocks dispatched first
    const int b = bh >> 3, h = bh & 7;
    const int tid = threadIdx.x;
    const int w = tid >> 6, l = tid & 63;
    const int col = l & 15, g = l >> 4;

    const unsigned char* kgb =
        reinterpret_cast<const unsigned char*>(Kp + (size_t)bh * S_LEN * HD);
    const unsigned char* vgb =
        reinterpret_cast<const unsigned char*>(Vt + (size_t)bh * HD * S_LEN);
    const int srow0 = tid >> 3, so0 = (tid & 7) * 16;
    const int srow1 = (tid + 256) >> 3, so1 = ((tid + 256) & 7) * 16;

    const int nt = qt + 1;

    // Q as B-frag (lane holds Q[q=col][d=8g..+8]), pre-scaled by log2e/8 in proj
    bf16x8 qf0, qf1;
    {
        const __bf16* qb = Qp + ((size_t)bh * S_LEN + qt * 64 + w * 16 + col) * HD + g * 8;
        qf0 = *reinterpret_cast<const bf16x8*>(qb);
        qf1 = *reinterpret_cast<const bf16x8*>(qb + 32);
    }
    // O^T accumulator: lane holds O^T[d = 16nf+4g+r][q = col]
    f32x4 oacc[4];
    #pragma unroll
    for (int nf = 0; nf < 4; ++nf) oacc[nf] = (f32x4){0.f, 0.f, 0.f, 0.f};
    float m = -1e30f, lsum = 0.f; // per-lane: q = col; lsum = partial over this lane's kv

    // bpermute addresses: src lane = col + 32*(g&1) (+16 for j>=2), byte addr = lane*4
    const int addrA = ((l & 15) + ((l & 16) << 1)) << 2;  // j<2
    const int addrB = addrA + (16 << 2);                  // j>=2
    const bool ghi = (l & 32) != 0;                       // dest needs wds[g>>1 (+2 for pf1)]

    uint4 kr0, kr1, vr0, vr1;
    kr0 = *reinterpret_cast<const uint4*>(kgb + tid * 16);
    kr1 = *reinterpret_cast<const uint4*>(kgb + (tid + 256) * 16);
    vr0 = *reinterpret_cast<const uint4*>(vgb + (size_t)srow0 * (S_LEN * 2) + so0);
    vr1 = *reinterpret_cast<const uint4*>(vgb + (size_t)srow1 * (S_LEN * 2) + so1);
    *reinterpret_cast<uint4*>(&kb[0][swz(srow0 * 128 + so0, srow0)]) = kr0;
    *reinterpret_cast<uint4*>(&kb[0][swz(srow1 * 128 + so1, srow1)]) = kr1;
    *reinterpret_cast<uint4*>(&vb[0][swz(srow0 * 128 + so0, srow0)]) = vr0;
    *reinterpret_cast<uint4*>(&vb[0][swz(srow1 * 128 + so1, srow1)]) = vr1;
    __syncthreads();

    int cur = 0;
    #pragma unroll 1
    for (int t = 0; t < nt; ++t) {
        const bool pf = (t + 1 < nt);
        if (pf) {
            const unsigned char* kg = kgb + (size_t)(t + 1) * 8192;
            const unsigned char* vg = vgb + (size_t)(t + 1) * 128;
            kr0 = *reinterpret_cast<const uint4*>(kg + tid * 16);
            kr1 = *reinterpret_cast<const uint4*>(kg + (tid + 256) * 16);
            vr0 = *reinterpret_cast<const uint4*>(vg + (size_t)srow0 * (S_LEN * 2) + so0);
            vr1 = *reinterpret_cast<const uint4*>(vg + (size_t)srow1 * (S_LEN * 2) + so1);
        }
        // S^T = K Q^T : lane holds S^T[kv = 16nf+4g+r][q = col]
        f32x4 sf[4];
        #pragma unroll
        for (int nf = 0; nf < 4; ++nf) sf[nf] = (f32x4){0.f, 0.f, 0.f, 0.f};
        #pragma unroll
        for (int nf = 0; nf < 4; ++nf) {
            int krow = nf * 16 + col;
            bf16x8 kf0 = *reinterpret_cast<const bf16x8*>(
                &kb[cur][swz(krow * 128 + g * 16, krow)]);
            bf16x8 kf1 = *reinterpret_cast<const bf16x8*>(
                &kb[cur][swz(krow * 128 + 64 + g * 16, krow)]);
            sf[nf] = __builtin_amdgcn_mfma_f32_16x16x32_bf16(kf0, qf0, sf[nf], 0, 0, 0);
            sf[nf] = __builtin_amdgcn_mfma_f32_16x16x32_bf16(kf1, qf1, sf[nf], 0, 0, 0);
        }
        if (t == qt) { // diagonal: mask kv_local > q_local (= w*16 + col)
            const int qloc = w * 16 + col;
            #pragma unroll
            for (int nf = 0; nf < 4; ++nf)
                #pragma unroll
                for (int r = 0; r < 4; ++r)
                    if (nf * 16 + g * 4 + r > qloc) sf[nf][r] = -1e30f;
        }
        // row(q)-max: local tree over 16 regs, then across the 4 lane-groups
        float rmax = fmaxf(fmaxf(fmaxf(sf[0][0], sf[0][1]), fmaxf(sf[0][2], sf[0][3])),
                           fmaxf(fmaxf(sf[1][0], sf[1][1]), fmaxf(sf[1][2], sf[1][3])));
        rmax = fmaxf(rmax,
               fmaxf(fmaxf(fmaxf(sf[2][0], sf[2][1]), fmaxf(sf[2][2], sf[2][3])),
                     fmaxf(fmaxf(sf[3][0], sf[3][1]), fmaxf(sf[3][2], sf[3][3]))));
        rmax = fmaxf(rmax, __shfl_xor(rmax, 16));
        rmax = fmaxf(rmax, __shfl_xor(rmax, 32));
        float mn = fmaxf(m, rmax);
        float sc = __builtin_exp2f(m - mn);
        m = mn;
        // P^T in-register: p = exp2(s - m); pack adjacent kv pairs to bf16x2 words
        float rsum = 0.f;
        int wds[4][2];
        #pragma unroll
        for (int nf = 0; nf < 4; ++nf) {
            float p0 = __builtin_exp2f(sf[nf][0] - m);
            float p1 = __builtin_exp2f(sf[nf][1] - m);
            float p2 = __builtin_exp2f(sf[nf][2] - m);
            float p3 = __builtin_exp2f(sf[nf][3] - m);
            rsum += (p0 + p1) + (p2 + p3);
            asm("v_cvt_pk_bf16_f32 %0, %1, %2" : "=v"(wds[nf][0]) : "v"(p0), "v"(p1));
            asm("v_cvt_pk_bf16_f32 %0, %1, %2" : "=v"(wds[nf][1]) : "v"(p2), "v"(p3));
        }
        lsum = lsum * sc + rsum;
        // redistribute to B-frag layout: dest word j needs P^T[kv=8g+2j..+1][q=col]
        // from src lane col+32*(g&1)+16*(j>>1), register wds[g>>1][j&1] (+2 for pf1).
        // bpermute is a PULL (value evaluated on SOURCE lane) -> pull BOTH nf'
        // candidates and select on the dest with ghi (round-5 bugfix).
        i32x4 bw0, bw1;
        #pragma unroll
        for (int j = 0; j < 4; ++j) {
            int a = (j < 2) ? addrA : addrB;
            int lo0 = __builtin_amdgcn_ds_bpermute(a, wds[0][j & 1]);
            int hi0 = __builtin_amdgcn_ds_bpermute(a, wds[1][j & 1]);
            int lo1 = __builtin_amdgcn_ds_bpermute(a, wds[2][j & 1]);
            int hi1 = __builtin_amdgcn_ds_bpermute(a, wds[3][j & 1]);
            bw0[j] = ghi ? hi0 : lo0;
            bw1[j] = ghi ? hi1 : lo1;
        }
        bf16x8 pf0, pf1;
        pf0 = *reinterpret_cast<bf16x8*>(&bw0);
        pf1 = *reinterpret_cast<bf16x8*>(&bw1);
        // rescale O^T
        #pragma unroll
        for (int nf = 0; nf < 4; ++nf)
            #pragma unroll
            for (int r = 0; r < 4; ++r) oacc[nf][r] *= sc;
        // O^T += V^T P^T : A-frag = V^T rows d (same LDS reads as before)
        #pragma unroll
        for (int nf = 0; nf < 4; ++nf) {
            int vrow = nf * 16 + col;
            bf16x8 vf0 = *reinterpret_cast<const bf16x8*>(
                &vb[cur][swz(vrow * 128 + g * 16, vrow)]);
            bf16x8 vf1 = *reinterpret_cast<const bf16x8*>(
                &vb[cur][swz(vrow * 128 + 64 + g * 16, vrow)]);
            oacc[nf] = __builtin_amdgcn_mfma_f32_16x16x32_bf16(vf0, pf0, oacc[nf], 0, 0, 0);
            oacc[nf] = __builtin_amdgcn_mfma_f32_16x16x32_bf16(vf1, pf1, oacc[nf], 0, 0, 0);
        }
        if (pf) {
            *reinterpret_cast<uint4*>(&kb[cur ^ 1][swz(srow0 * 128 + so0, srow0)]) = kr0;
            *reinterpret_cast<uint4*>(&kb[cur ^ 1][swz(srow1 * 128 + so1, srow1)]) = kr1;
            *reinterpret_cast<uint4*>(&vb[cur ^ 1][swz(srow0 * 128 + so0, srow0)]) = vr0;
            *reinterpret_cast<uint4*>(&vb[cur ^ 1][swz(srow1 * 128 + so1, srow1)]) = vr1;
        }
        __syncthreads();
        cur ^= 1;
    }
    // final: reduce lsum across the 4 lane-groups, normalize, store O^T
    lsum += __shfl_xor(lsum, 16);
    lsum += __shfl_xor(lsum, 32);
    float inv = 1.0f / lsum;
    const int s = qt * 64 + w * 16 + col;
    __bf16* ob = Oa + ((size_t)b * S_LEN + s) * EMB + h * HD + g * 4;
    #pragma unroll
    for (int nf = 0; nf < 4; ++nf) {
        bf16x4 o;
        #pragma unroll
        for (int r = 0; r < 4; ++r) o[r] = (__bf16)(oacc[nf][r] * inv);
        *reinterpret_cast<bf16x4*>(ob + nf * 16) = o;
    }
}

__global__ __launch_bounds__(256) void fc_kernel(
    const __bf16* __restrict__ A,   // Oattn [B*S][E] bf16
    const float* __restrict__ Wfc,  // [E][E] fp32, row-major (n, k)
    const float* __restrict__ bfc,  // [E]
    float* __restrict__ out)        // [B*S][E] fp32
{
    __shared__ alignas(16) unsigned char ab[8192]; // A tile 64x64 bf16, swizzled
    __shared__ alignas(16) unsigned char bb[8192]; // W tile 64x64 bf16, swizzled
    const int r0 = blockIdx.x << 6;
    const int n0 = blockIdx.y << 6;
    const int tid = threadIdx.x;
    const int w = tid >> 6, l = tid & 63;
    const int col = l & 15, g = l >> 4;

    f32x4 acc[4];
    #pragma unroll
    for (int nf = 0; nf < 4; ++nf) acc[nf] = (f32x4){0.f, 0.f, 0.f, 0.f};

    for (int kc = 0; kc < 8; ++kc) {
        __syncthreads();
        #pragma unroll
        for (int it = 0; it < 2; ++it) {
            int c = tid + it * 256;
            int row = c >> 3, o = (c & 7) * 16;
            uint4 d = *reinterpret_cast<const uint4*>(
                reinterpret_cast<const unsigned char*>(A) +
                ((size_t)(r0 + row) * EMB + kc * 64) * 2 + o);
            *reinterpret_cast<uint4*>(&ab[swz(row * 128 + o, row)]) = d;
        }
        #pragma unroll
        for (int it = 0; it < 4; ++it) {
            int c = tid + it * 256;
            int row = c >> 4, c4 = c & 15;
            float4 f = *reinterpret_cast<const float4*>(
                Wfc + (size_t)(n0 + row) * EMB + kc * 64 + c4 * 4);
            bf16x4 t;
            t[0] = (__bf16)f.x; t[1] = (__bf16)f.y; t[2] = (__bf16)f.z; t[3] = (__bf16)f.w;
            *reinterpret_cast<bf16x4*>(&bb[swz(row * 128 + c4 * 8, row)]) = t;
        }
        __syncthreads();
        int arow = w * 16 + col;
        #pragma unroll
        for (int ks = 0; ks < 2; ++ks) {
            bf16x8 af = *reinterpret_cast<const bf16x8*>(
                &ab[swz(arow * 128 + ks * 64 + g * 16, arow)]);
            #pragma unroll
            for (int nf = 0; nf < 4; ++nf) {
                int brow = nf * 16 + col;
                bf16x8 bf = *reinterpret_cast<const bf16x8*>(
                    &bb[swz(brow * 128 + ks * 64 + g * 16, brow)]);
                acc[nf] = __builtin_amdgcn_mfma_f32_16x16x32_bf16(af, bf, acc[nf], 0, 0, 0);
            }
        }
    }
    #pragma unroll
    for (int nf = 0; nf < 4; ++nf) {
        float bias = bfc[n0 + nf * 16 + col];
        #pragma unroll
        for (int r = 0; r < 4; ++r) {
            int row = r0 + w * 16 + g * 4 + r;
            out[(size_t)row * EMB + n0 + nf * 16 + col] = acc[nf][r] + bias;
        }
    }
}

extern "C" void kernel_launch(void* const* d_in, const int* in_sizes, int n_in,
                              void* d_out, int out_size, void* d_ws, size_t ws_size,
                              hipStream_t stream) {
    const float* q   = (const float*)d_in[0];
    const float* k   = (const float*)d_in[1];
    const float* v   = (const float*)d_in[2];
    const float* Wq  = (const float*)d_in[3];
    const float* Wk  = (const float*)d_in[4];
    const float* Wv  = (const float*)d_in[5];
    const float* Wfc = (const float*)d_in[6];
    const float* bfc = (const float*)d_in[7];
    float* out = (float*)d_out;

    char* ws = (char*)d_ws;
    const size_t SZ = (size_t)4 * NH * S_LEN * HD * sizeof(__bf16); // 8 MiB
    __bf16* Qp = (__bf16*)(ws);
    __bf16* Kp = (__bf16*)(ws + SZ);
    __bf16* Vt = (__bf16*)(ws + 2 * SZ);
    __bf16* Oa = (__bf16*)(ws + 3 * SZ);

    proj_kernel<<<dim3(S_LEN / 64, 4 * NH), 256, 0, stream>>>(q, k, v, Wq, Wk, Wv, Qp, Kp, Vt);
    attn_kernel<<<dim3(32 * 32), 256, 0, stream>>>(Qp, Kp, Vt, Oa);
    fc_kernel<<<dim3((4 * S_LEN) / 64, EMB / 64), 256, 0, stream>>>(Oa, Wfc, bfc, out);
}

// Round 7
// 107.073 us; speedup vs baseline: 2.0802x; 1.0075x over previous
//
#include <hip/hip_runtime.h>
#include <hip/hip_bf16.h>

// MultiHeadAttention B=4 S=2048 E=512 H=8 D=64, causal. Inputs fp32, output fp32.
// 3-kernel bf16-MFMA pipeline:
//   proj: X @ W^T per head; Qp pre-scaled by log2(e)/8; Qp/Kp [bh][s][d], Vt [bh][d][s]
//   attn: flash attention in TRANSPOSED space; 512-thread blocks, 2 wave-groups
//         split the KV range (even/odd tiles) -> serial critical path halved;
//         flash partial-merge in LDS at block end; LPT grid + XCD-affine bh,
//         per-group dbuf K/V LDS, 1 barrier/tile, reg-prefetch
//   fc:   [8192,512] @ Wfc^T + bias -> fp32 out
#define S_LEN 2048
#define EMB 512
#define NH 8
#define HD 64

typedef __bf16 bf16x8 __attribute__((ext_vector_type(8)));
typedef __bf16 bf16x4 __attribute__((ext_vector_type(4)));
typedef float f32x4 __attribute__((ext_vector_type(4)));
typedef int i32x4 __attribute__((ext_vector_type(4)));

__device__ __forceinline__ unsigned swz(unsigned byteoff, unsigned row) {
    return byteoff ^ ((row & 7u) << 4);
}

__global__ __launch_bounds__(256) void proj_kernel(
    const float* __restrict__ qin, const float* __restrict__ kin, const float* __restrict__ vin,
    const float* __restrict__ Wq, const float* __restrict__ Wk, const float* __restrict__ Wv,
    __bf16* __restrict__ Qp, __bf16* __restrict__ Kp, __bf16* __restrict__ Vt)
{
    __shared__ alignas(16) unsigned char xb[3][8192]; // 64x64 bf16 tiles (q,k,v rows), swizzled
    __shared__ alignas(16) unsigned char tb[8192];    // v-proj output tile for transpose, linear
    const int bh = blockIdx.y;
    const int b = bh >> 3, h = bh & 7;
    const int sblk = blockIdx.x << 6;
    const int tid = threadIdx.x;
    const int w = tid >> 6, l = tid & 63;
    const int col = l & 15, g = l >> 4;
    const float K1 = 0.18033688011112042f; // log2(e)/8 folded into Qp

    const float* srcs[3] = {qin, kin, vin};
    #pragma unroll
    for (int p = 0; p < 3; ++p) {
        const float* src = srcs[p] + ((size_t)b * S_LEN + sblk) * EMB + h * HD;
        #pragma unroll
        for (int it = 0; it < 4; ++it) {
            int c = tid + it * 256;            // 1024 float4 chunks = 64 rows x 16
            int row = c >> 4, c4 = c & 15;
            float4 f = *reinterpret_cast<const float4*>(src + (size_t)row * EMB + c4 * 4);
            bf16x4 t;
            t[0] = (__bf16)f.x; t[1] = (__bf16)f.y; t[2] = (__bf16)f.z; t[3] = (__bf16)f.w;
            *reinterpret_cast<bf16x4*>(&xb[p][swz(row * 128 + c4 * 8, row)]) = t;
        }
    }
    __syncthreads();

    const float* Ws[3] = {Wq, Wk, Wv};
    #pragma unroll
    for (int p = 0; p < 3; ++p) {
        bf16x8 wf[4][2];
        #pragma unroll
        for (int nf = 0; nf < 4; ++nf)
            #pragma unroll
            for (int ks = 0; ks < 2; ++ks) {
                const float* base = Ws[p] + (nf * 16 + col) * HD + ks * 32 + g * 8;
                float4 f0 = *reinterpret_cast<const float4*>(base);
                float4 f1 = *reinterpret_cast<const float4*>(base + 4);
                bf16x8 r;
                r[0] = (__bf16)f0.x; r[1] = (__bf16)f0.y; r[2] = (__bf16)f0.z; r[3] = (__bf16)f0.w;
                r[4] = (__bf16)f1.x; r[5] = (__bf16)f1.y; r[6] = (__bf16)f1.z; r[7] = (__bf16)f1.w;
                wf[nf][ks] = r;
            }
        int arow = w * 16 + col;
        bf16x8 a0 = *reinterpret_cast<const bf16x8*>(&xb[p][swz(arow * 128 + g * 16, arow)]);
        bf16x8 a1 = *reinterpret_cast<const bf16x8*>(&xb[p][swz(arow * 128 + 64 + g * 16, arow)]);
        f32x4 acc[4];
        #pragma unroll
        for (int nf = 0; nf < 4; ++nf) acc[nf] = (f32x4){0.f, 0.f, 0.f, 0.f};
        #pragma unroll
        for (int nf = 0; nf < 4; ++nf) {
            acc[nf] = __builtin_amdgcn_mfma_f32_16x16x32_bf16(a0, wf[nf][0], acc[nf], 0, 0, 0);
            acc[nf] = __builtin_amdgcn_mfma_f32_16x16x32_bf16(a1, wf[nf][1], acc[nf], 0, 0, 0);
        }
        if (p < 2) {
            __bf16* dst = (p == 0 ? Qp : Kp);
            const float s0 = (p == 0) ? K1 : 1.0f; // fold softmax scale into Q
            #pragma unroll
            for (int nf = 0; nf < 4; ++nf)
                #pragma unroll
                for (int r = 0; r < 4; ++r) {
                    int srow = sblk + w * 16 + g * 4 + r;
                    dst[((size_t)bh * S_LEN + srow) * HD + nf * 16 + col] =
                        (__bf16)(acc[nf][r] * s0);
                }
        } else {
            #pragma unroll
            for (int nf = 0; nf < 4; ++nf)
                #pragma unroll
                for (int r = 0; r < 4; ++r) {
                    int srow = w * 16 + g * 4 + r;
                    *reinterpret_cast<__bf16*>(&tb[(srow * 64 + nf * 16 + col) * 2]) =
                        (__bf16)acc[nf][r];
                }
        }
    }
    __syncthreads();
    {
        int e = tid & 63, sc = tid >> 6;
        bf16x8 lo, hi;
        #pragma unroll
        for (int i = 0; i < 8; ++i)
            lo[i] = *reinterpret_cast<const __bf16*>(&tb[((sc * 16 + i) * 64 + e) * 2]);
        #pragma unroll
        for (int i = 0; i < 8; ++i)
            hi[i] = *reinterpret_cast<const __bf16*>(&tb[((sc * 16 + 8 + i) * 64 + e) * 2]);
        __bf16* dst = Vt + ((size_t)bh * HD + e) * S_LEN + sblk + sc * 16;
        *reinterpret_cast<bf16x8*>(dst) = lo;
        *reinterpret_cast<bf16x8*>(dst + 8) = hi;
    }
}

__global__ __launch_bounds__(512) void attn_kernel(
    const __bf16* __restrict__ Qp, const __bf16* __restrict__ Kp,
    const __bf16* __restrict__ Vt, __bf16* __restrict__ Oa)
{
    // per-group dbuf K/V tiles; reused as merge buffers after the loop
    __shared__ alignas(16) unsigned char kb[2][2][8192]; // [group][dbuf] K [kv][d]
    __shared__ alignas(16) unsigned char vb[2][2][8192]; // [group][dbuf] V^T [d][kv]
    const int l_id = blockIdx.x;
    const int bh = l_id & 31;            // XCD-affine: same-bh blocks share l%8
    const int qt = 31 - (l_id >> 5);     // LPT: longest blocks dispatched first
    const int b = bh >> 3, h = bh & 7;
    const int tid = threadIdx.x;
    const int w = tid >> 6, l = tid & 63;
    const int wq = w & 3, g2 = w >> 3 ? 1 : (w >> 2); // w in 0..7 -> g2 = w>>2
    const int col = l & 15, g = l >> 4;

    const unsigned char* kgb =
        reinterpret_cast<const unsigned char*>(Kp + (size_t)bh * S_LEN * HD);
    const unsigned char* vgb =
        reinterpret_cast<const unsigned char*>(Vt + (size_t)bh * HD * S_LEN);
    const int ts = tid & 255; // group-local staging id (256 threads per group)
    const int srow0 = ts >> 3, so0 = (ts & 7) * 16;
    const int srow1 = (ts + 256) >> 3, so1 = ((ts + 256) & 7) * 16;

    // Q as B-frag (lane holds Q[q = wq*16+col][d=8g..+8]), pre-scaled by log2e/8
    bf16x8 qf0, qf1;
    {
        const __bf16* qb = Qp + ((size_t)bh * S_LEN + qt * 64 + wq * 16 + col) * HD + g * 8;
        qf0 = *reinterpret_cast<const bf16x8*>(qb);
        qf1 = *reinterpret_cast<const bf16x8*>(qb + 32);
    }
    // O^T accumulator: lane holds O^T[d = 16nf+4g+r][q = col] over this group's kv
    f32x4 oacc[4];
    #pragma unroll
    for (int nf = 0; nf < 4; ++nf) oacc[nf] = (f32x4){0.f, 0.f, 0.f, 0.f};
    float m = -1e30f, lsum = 0.f;

    const int addrA = ((l & 15) + ((l & 16) << 1)) << 2;
    const int addrB = addrA + (16 << 2);
    const bool ghi = (l & 32) != 0;

    uint4 kr0, kr1, vr0, vr1;
    if (g2 <= qt) { // prologue: stage this group's first tile (t = g2) into buf 0
        const unsigned char* kg = kgb + (size_t)g2 * 8192;
        const unsigned char* vg = vgb + (size_t)g2 * 128;
        kr0 = *reinterpret_cast<const uint4*>(kg + ts * 16);
        kr1 = *reinterpret_cast<const uint4*>(kg + (ts + 256) * 16);
        vr0 = *reinterpret_cast<const uint4*>(vg + (size_t)srow0 * (S_LEN * 2) + so0);
        vr1 = *reinterpret_cast<const uint4*>(vg + (size_t)srow1 * (S_LEN * 2) + so1);
        *reinterpret_cast<uint4*>(&kb[g2][0][swz(srow0 * 128 + so0, srow0)]) = kr0;
        *reinterpret_cast<uint4*>(&kb[g2][0][swz(srow1 * 128 + so1, srow1)]) = kr1;
        *reinterpret_cast<uint4*>(&vb[g2][0][swz(srow0 * 128 + so0, srow0)]) = vr0;
        *reinterpret_cast<uint4*>(&vb[g2][0][swz(srow1 * 128 + so1, srow1)]) = vr1;
    }
    __syncthreads();

    int cur = 0;
    const int niter = (qt >> 1) + 1;
    #pragma unroll 1
    for (int i = 0; i < niter; ++i) {
        const int t = 2 * i + g2;           // this group's kv tile
        const bool active = (t <= qt);
        const int t2 = t + 2;
        const bool pfv = (t2 <= qt);
        if (pfv) {
            const unsigned char* kg = kgb + (size_t)t2 * 8192;
            const unsigned char* vg = vgb + (size_t)t2 * 128;
            kr0 = *reinterpret_cast<const uint4*>(kg + ts * 16);
            kr1 = *reinterpret_cast<const uint4*>(kg + (ts + 256) * 16);
            vr0 = *reinterpret_cast<const uint4*>(vg + (size_t)srow0 * (S_LEN * 2) + so0);
            vr1 = *reinterpret_cast<const uint4*>(vg + (size_t)srow1 * (S_LEN * 2) + so1);
        }
        if (active) {
            // S^T = K Q^T : lane holds S^T[kv = 16nf+4g+r][q = col]
            f32x4 sf[4];
            #pragma unroll
            for (int nf = 0; nf < 4; ++nf) sf[nf] = (f32x4){0.f, 0.f, 0.f, 0.f};
            #pragma unroll
            for (int nf = 0; nf < 4; ++nf) {
                int krow = nf * 16 + col;
                bf16x8 kf0 = *reinterpret_cast<const bf16x8*>(
                    &kb[g2][cur][swz(krow * 128 + g * 16, krow)]);
                bf16x8 kf1 = *reinterpret_cast<const bf16x8*>(
                    &kb[g2][cur][swz(krow * 128 + 64 + g * 16, krow)]);
                sf[nf] = __builtin_amdgcn_mfma_f32_16x16x32_bf16(kf0, qf0, sf[nf], 0, 0, 0);
                sf[nf] = __builtin_amdgcn_mfma_f32_16x16x32_bf16(kf1, qf1, sf[nf], 0, 0, 0);
            }
            if (t == qt) { // diagonal: mask kv_local > q_local (= wq*16 + col)
                const int qloc = wq * 16 + col;
                #pragma unroll
                for (int nf = 0; nf < 4; ++nf)
                    #pragma unroll
                    for (int r = 0; r < 4; ++r)
                        if (nf * 16 + g * 4 + r > qloc) sf[nf][r] = -1e30f;
            }
            float rmax = fmaxf(fmaxf(fmaxf(sf[0][0], sf[0][1]), fmaxf(sf[0][2], sf[0][3])),
                               fmaxf(fmaxf(sf[1][0], sf[1][1]), fmaxf(sf[1][2], sf[1][3])));
            rmax = fmaxf(rmax,
                   fmaxf(fmaxf(fmaxf(sf[2][0], sf[2][1]), fmaxf(sf[2][2], sf[2][3])),
                         fmaxf(fmaxf(sf[3][0], sf[3][1]), fmaxf(sf[3][2], sf[3][3]))));
            rmax = fmaxf(rmax, __shfl_xor(rmax, 16));
            rmax = fmaxf(rmax, __shfl_xor(rmax, 32));
            float mn = fmaxf(m, rmax);
            float sc = __builtin_exp2f(m - mn);
            m = mn;
            float rsum = 0.f;
            int wds[4][2];
            #pragma unroll
            for (int nf = 0; nf < 4; ++nf) {
                float p0 = __builtin_exp2f(sf[nf][0] - m);
                float p1 = __builtin_exp2f(sf[nf][1] - m);
                float p2 = __builtin_exp2f(sf[nf][2] - m);
                float p3 = __builtin_exp2f(sf[nf][3] - m);
                rsum += (p0 + p1) + (p2 + p3);
                asm("v_cvt_pk_bf16_f32 %0, %1, %2" : "=v"(wds[nf][0]) : "v"(p0), "v"(p1));
                asm("v_cvt_pk_bf16_f32 %0, %1, %2" : "=v"(wds[nf][1]) : "v"(p2), "v"(p3));
            }
            lsum = lsum * sc + rsum;
            // B-frag redistribution: pull both nf' candidates, select with ghi
            i32x4 bw0, bw1;
            #pragma unroll
            for (int j = 0; j < 4; ++j) {
                int a = (j < 2) ? addrA : addrB;
                int lo0 = __builtin_amdgcn_ds_bpermute(a, wds[0][j & 1]);
                int hi0 = __builtin_amdgcn_ds_bpermute(a, wds[1][j & 1]);
                int lo1 = __builtin_amdgcn_ds_bpermute(a, wds[2][j & 1]);
                int hi1 = __builtin_amdgcn_ds_bpermute(a, wds[3][j & 1]);
                bw0[j] = ghi ? hi0 : lo0;
                bw1[j] = ghi ? hi1 : lo1;
            }
            bf16x8 pf0, pf1;
            pf0 = *reinterpret_cast<bf16x8*>(&bw0);
            pf1 = *reinterpret_cast<bf16x8*>(&bw1);
            #pragma unroll
            for (int nf = 0; nf < 4; ++nf)
                #pragma unroll
                for (int r = 0; r < 4; ++r) oacc[nf][r] *= sc;
            #pragma unroll
            for (int nf = 0; nf < 4; ++nf) {
                int vrow = nf * 16 + col;
                bf16x8 vf0 = *reinterpret_cast<const bf16x8*>(
                    &vb[g2][cur][swz(vrow * 128 + g * 16, vrow)]);
                bf16x8 vf1 = *reinterpret_cast<const bf16x8*>(
                    &vb[g2][cur][swz(vrow * 128 + 64 + g * 16, vrow)]);
                oacc[nf] = __builtin_amdgcn_mfma_f32_16x16x32_bf16(vf0, pf0, oacc[nf], 0, 0, 0);
                oacc[nf] = __builtin_amdgcn_mfma_f32_16x16x32_bf16(vf1, pf1, oacc[nf], 0, 0, 0);
            }
        }
        if (pfv) {
            *reinterpret_cast<uint4*>(&kb[g2][cur ^ 1][swz(srow0 * 128 + so0, srow0)]) = kr0;
            *reinterpret_cast<uint4*>(&kb[g2][cur ^ 1][swz(srow1 * 128 + so1, srow1)]) = kr1;
            *reinterpret_cast<uint4*>(&vb[g2][cur ^ 1][swz(srow0 * 128 + so0, srow0)]) = vr0;
            *reinterpret_cast<uint4*>(&vb[g2][cur ^ 1][swz(srow1 * 128 + so1, srow1)]) = vr1;
        }
        __syncthreads();
        cur ^= 1;
    }

    // flash partial-merge across the 2 kv groups (loop ended with a barrier,
    // so kb/vb are free to reuse; lane-contiguous layout = conflict-free)
    float* obuf = reinterpret_cast<float*>(&kb[0][0][0]); // 4096 f32 = 16 KB
    float* mbuf = reinterpret_cast<float*>(&vb[0][0][0]); // 512 f32
    const int lane256 = wq * 64 + l;
    if (g2 == 1) {
        #pragma unroll
        for (int nf = 0; nf < 4; ++nf)
            #pragma unroll
            for (int r = 0; r < 4; ++r)
                obuf[(nf * 4 + r) * 256 + lane256] = oacc[nf][r];
        mbuf[lane256] = m;
        mbuf[256 + lane256] = lsum;
    }
    __syncthreads();
    if (g2 == 0) {
        float mB = mbuf[lane256], lB = mbuf[256 + lane256];
        float M = fmaxf(m, mB);
        float eA = __builtin_exp2f(m - M);
        float eB = __builtin_exp2f(mB - M);
        lsum = eA * lsum + eB * lB;
        #pragma unroll
        for (int nf = 0; nf < 4; ++nf)
            #pragma unroll
            for (int r = 0; r < 4; ++r)
                oacc[nf][r] = eA * oacc[nf][r] + eB * obuf[(nf * 4 + r) * 256 + lane256];
        lsum += __shfl_xor(lsum, 16);
        lsum += __shfl_xor(lsum, 32);
        float inv = 1.0f / lsum;
        const int s = qt * 64 + wq * 16 + col;
        __bf16* op = Oa + ((size_t)b * S_LEN + s) * EMB + h * HD + g * 4;
        #pragma unroll
        for (int nf = 0; nf < 4; ++nf) {
            bf16x4 o;
            #pragma unroll
            for (int r = 0; r < 4; ++r) o[r] = (__bf16)(oacc[nf][r] * inv);
            *reinterpret_cast<bf16x4*>(op + nf * 16) = o;
        }
    }
}

__global__ __launch_bounds__(256) void fc_kernel(
    const __bf16* __restrict__ A,   // Oattn [B*S][E] bf16
    const float* __restrict__ Wfc,  // [E][E] fp32, row-major (n, k)
    const float* __restrict__ bfc,  // [E]
    float* __restrict__ out)        // [B*S][E] fp32
{
    __shared__ alignas(16) unsigned char ab[8192]; // A tile 64x64 bf16, swizzled
    __shared__ alignas(16) unsigned char bb[8192]; // W tile 64x64 bf16, swizzled
    const int r0 = blockIdx.x << 6;
    const int n0 = blockIdx.y << 6;
    const int tid = threadIdx.x;
    const int w = tid >> 6, l = tid & 63;
    const int col = l & 15, g = l >> 4;

    f32x4 acc[4];
    #pragma unroll
    for (int nf = 0; nf < 4; ++nf) acc[nf] = (f32x4){0.f, 0.f, 0.f, 0.f};

    for (int kc = 0; kc < 8; ++kc) {
        __syncthreads();
        #pragma unroll
        for (int it = 0; it < 2; ++it) {
            int c = tid + it * 256;
            int row = c >> 3, o = (c & 7) * 16;
            uint4 d = *reinterpret_cast<const uint4*>(
                reinterpret_cast<const unsigned char*>(A) +
                ((size_t)(r0 + row) * EMB + kc * 64) * 2 + o);
            *reinterpret_cast<uint4*>(&ab[swz(row * 128 + o, row)]) = d;
        }
        #pragma unroll
        for (int it = 0; it < 4; ++it) {
            int c = tid + it * 256;
            int row = c >> 4, c4 = c & 15;
            float4 f = *reinterpret_cast<const float4*>(
                Wfc + (size_t)(n0 + row) * EMB + kc * 64 + c4 * 4);
            bf16x4 t;
            t[0] = (__bf16)f.x; t[1] = (__bf16)f.y; t[2] = (__bf16)f.z; t[3] = (__bf16)f.w;
            *reinterpret_cast<bf16x4*>(&bb[swz(row * 128 + c4 * 8, row)]) = t;
        }
        __syncthreads();
        int arow = w * 16 + col;
        #pragma unroll
        for (int ks = 0; ks < 2; ++ks) {
            bf16x8 af = *reinterpret_cast<const bf16x8*>(
                &ab[swz(arow * 128 + ks * 64 + g * 16, arow)]);
            #pragma unroll
            for (int nf = 0; nf < 4; ++nf) {
                int brow = nf * 16 + col;
                bf16x8 bf = *reinterpret_cast<const bf16x8*>(
                    &bb[swz(brow * 128 + ks * 64 + g * 16, brow)]);
                acc[nf] = __builtin_amdgcn_mfma_f32_16x16x32_bf16(af, bf, acc[nf], 0, 0, 0);
            }
        }
    }
    #pragma unroll
    for (int nf = 0; nf < 4; ++nf) {
        float bias = bfc[n0 + nf * 16 + col];
        #pragma unroll
        for (int r = 0; r < 4; ++r) {
            int row = r0 + w * 16 + g * 4 + r;
            out[(size_t)row * EMB + n0 + nf * 16 + col] = acc[nf][r] + bias;
        }
    }
}

extern "C" void kernel_launch(void* const* d_in, const int* in_sizes, int n_in,
                              void* d_out, int out_size, void* d_ws, size_t ws_size,
                              hipStream_t stream) {
    const float* q   = (const float*)d_in[0];
    const float* k   = (const float*)d_in[1];
    const float* v   = (const float*)d_in[2];
    const float* Wq  = (const float*)d_in[3];
    const float* Wk  = (const float*)d_in[4];
    const float* Wv  = (const float*)d_in[5];
    const float* Wfc = (const float*)d_in[6];
    const float* bfc = (const float*)d_in[7];
    float* out = (float*)d_out;

    char* ws = (char*)d_ws;
    const size_t SZ = (size_t)4 * NH * S_LEN * HD * sizeof(__bf16); // 8 MiB
    __bf16* Qp = (__bf16*)(ws);
    __bf16* Kp = (__bf16*)(ws + SZ);
    __bf16* Vt = (__bf16*)(ws + 2 * SZ);
    __bf16* Oa = (__bf16*)(ws + 3 * SZ);

    proj_kernel<<<dim3(S_LEN / 64, 4 * NH), 256, 0, stream>>>(q, k, v, Wq, Wk, Wv, Qp, Kp, Vt);
    attn_kernel<<<dim3(32 * 32), 512, 0, stream>>>(Qp, Kp, Vt, Oa);
    fc_kernel<<<dim3((4 * S_LEN) / 64, EMB / 64), 256, 0, stream>>>(Oa, Wfc, bfc, out);
}

// Round 8
// 105.908 us; speedup vs baseline: 2.1031x; 1.0110x over previous
//
#include <hip/hip_runtime.h>
#include <hip/hip_bf16.h>

// MultiHeadAttention B=4 S=2048 E=512 H=8 D=64, causal. Inputs fp32, output fp32.
// 3-kernel bf16-MFMA pipeline:
//   proj: X @ W^T per head; Qp pre-scaled by log2(e)/8; Qp/Kp [bh][s][d], Vt [bh][d][s]
//   attn: flash attention in TRANSPOSED space; 512-thread blocks, 2 wave-groups split
//         the KV range (even/odd tiles); SINGLE-buffered per-group K/V LDS (32KB/block
//         -> 4 blocks/CU, 8 waves/SIMD) with T14 issue-early/write-late; flash
//         partial-merge in LDS at block end; LPT grid + XCD-affine bh
//   fc:   [8192,512] @ Wfc^T + bias -> fp32 out
#define S_LEN 2048
#define EMB 512
#define NH 8
#define HD 64

typedef __bf16 bf16x8 __attribute__((ext_vector_type(8)));
typedef __bf16 bf16x4 __attribute__((ext_vector_type(4)));
typedef float f32x4 __attribute__((ext_vector_type(4)));
typedef int i32x4 __attribute__((ext_vector_type(4)));

__device__ __forceinline__ unsigned swz(unsigned byteoff, unsigned row) {
    return byteoff ^ ((row & 7u) << 4);
}

__global__ __launch_bounds__(256) void proj_kernel(
    const float* __restrict__ qin, const float* __restrict__ kin, const float* __restrict__ vin,
    const float* __restrict__ Wq, const float* __restrict__ Wk, const float* __restrict__ Wv,
    __bf16* __restrict__ Qp, __bf16* __restrict__ Kp, __bf16* __restrict__ Vt)
{
    __shared__ alignas(16) unsigned char xb[3][8192]; // 64x64 bf16 tiles (q,k,v rows), swizzled
    __shared__ alignas(16) unsigned char tb[8192];    // v-proj output tile for transpose, linear
    const int bh = blockIdx.y;
    const int b = bh >> 3, h = bh & 7;
    const int sblk = blockIdx.x << 6;
    const int tid = threadIdx.x;
    const int w = tid >> 6, l = tid & 63;
    const int col = l & 15, g = l >> 4;
    const float K1 = 0.18033688011112042f; // log2(e)/8 folded into Qp

    const float* srcs[3] = {qin, kin, vin};
    #pragma unroll
    for (int p = 0; p < 3; ++p) {
        const float* src = srcs[p] + ((size_t)b * S_LEN + sblk) * EMB + h * HD;
        #pragma unroll
        for (int it = 0; it < 4; ++it) {
            int c = tid + it * 256;            // 1024 float4 chunks = 64 rows x 16
            int row = c >> 4, c4 = c & 15;
            float4 f = *reinterpret_cast<const float4*>(src + (size_t)row * EMB + c4 * 4);
            bf16x4 t;
            t[0] = (__bf16)f.x; t[1] = (__bf16)f.y; t[2] = (__bf16)f.z; t[3] = (__bf16)f.w;
            *reinterpret_cast<bf16x4*>(&xb[p][swz(row * 128 + c4 * 8, row)]) = t;
        }
    }
    __syncthreads();

    const float* Ws[3] = {Wq, Wk, Wv};
    #pragma unroll
    for (int p = 0; p < 3; ++p) {
        bf16x8 wf[4][2];
        #pragma unroll
        for (int nf = 0; nf < 4; ++nf)
            #pragma unroll
            for (int ks = 0; ks < 2; ++ks) {
                const float* base = Ws[p] + (nf * 16 + col) * HD + ks * 32 + g * 8;
                float4 f0 = *reinterpret_cast<const float4*>(base);
                float4 f1 = *reinterpret_cast<const float4*>(base + 4);
                bf16x8 r;
                r[0] = (__bf16)f0.x; r[1] = (__bf16)f0.y; r[2] = (__bf16)f0.z; r[3] = (__bf16)f0.w;
                r[4] = (__bf16)f1.x; r[5] = (__bf16)f1.y; r[6] = (__bf16)f1.z; r[7] = (__bf16)f1.w;
                wf[nf][ks] = r;
            }
        int arow = w * 16 + col;
        bf16x8 a0 = *reinterpret_cast<const bf16x8*>(&xb[p][swz(arow * 128 + g * 16, arow)]);
        bf16x8 a1 = *reinterpret_cast<const bf16x8*>(&xb[p][swz(arow * 128 + 64 + g * 16, arow)]);
        f32x4 acc[4];
        #pragma unroll
        for (int nf = 0; nf < 4; ++nf) acc[nf] = (f32x4){0.f, 0.f, 0.f, 0.f};
        #pragma unroll
        for (int nf = 0; nf < 4; ++nf) {
            acc[nf] = __builtin_amdgcn_mfma_f32_16x16x32_bf16(a0, wf[nf][0], acc[nf], 0, 0, 0);
            acc[nf] = __builtin_amdgcn_mfma_f32_16x16x32_bf16(a1, wf[nf][1], acc[nf], 0, 0, 0);
        }
        if (p < 2) {
            __bf16* dst = (p == 0 ? Qp : Kp);
            const float s0 = (p == 0) ? K1 : 1.0f; // fold softmax scale into Q
            #pragma unroll
            for (int nf = 0; nf < 4; ++nf)
                #pragma unroll
                for (int r = 0; r < 4; ++r) {
                    int srow = sblk + w * 16 + g * 4 + r;
                    dst[((size_t)bh * S_LEN + srow) * HD + nf * 16 + col] =
                        (__bf16)(acc[nf][r] * s0);
                }
        } else {
            #pragma unroll
            for (int nf = 0; nf < 4; ++nf)
                #pragma unroll
                for (int r = 0; r < 4; ++r) {
                    int srow = w * 16 + g * 4 + r;
                    *reinterpret_cast<__bf16*>(&tb[(srow * 64 + nf * 16 + col) * 2]) =
                        (__bf16)acc[nf][r];
                }
        }
    }
    __syncthreads();
    {
        int e = tid & 63, sc = tid >> 6;
        bf16x8 lo, hi;
        #pragma unroll
        for (int i = 0; i < 8; ++i)
            lo[i] = *reinterpret_cast<const __bf16*>(&tb[((sc * 16 + i) * 64 + e) * 2]);
        #pragma unroll
        for (int i = 0; i < 8; ++i)
            hi[i] = *reinterpret_cast<const __bf16*>(&tb[((sc * 16 + 8 + i) * 64 + e) * 2]);
        __bf16* dst = Vt + ((size_t)bh * HD + e) * S_LEN + sblk + sc * 16;
        *reinterpret_cast<bf16x8*>(dst) = lo;
        *reinterpret_cast<bf16x8*>(dst + 8) = hi;
    }
}

__global__ __launch_bounds__(512) void attn_kernel(
    const __bf16* __restrict__ Qp, const __bf16* __restrict__ Kp,
    const __bf16* __restrict__ Vt, __bf16* __restrict__ Oa)
{
    // per-group SINGLE-buffered K/V tiles (T14 issue-early/write-late);
    // reused as merge buffers after the loop
    __shared__ alignas(16) unsigned char kb[2][8192]; // [group] K [kv][d], swizzled
    __shared__ alignas(16) unsigned char vb[2][8192]; // [group] V^T [d][kv], swizzled
    const int l_id = blockIdx.x;
    const int bh = l_id & 31;            // XCD-affine: same-bh blocks share l%8
    const int qt = 31 - (l_id >> 5);     // LPT: longest blocks dispatched first
    const int b = bh >> 3, h = bh & 7;
    const int tid = threadIdx.x;
    const int w = tid >> 6, l = tid & 63;
    const int wq = w & 3, g2 = w >> 2;   // wave -> (q-slice, kv-group)
    const int col = l & 15, g = l >> 4;

    const unsigned char* kgb =
        reinterpret_cast<const unsigned char*>(Kp + (size_t)bh * S_LEN * HD);
    const unsigned char* vgb =
        reinterpret_cast<const unsigned char*>(Vt + (size_t)bh * HD * S_LEN);
    const int ts = tid & 255; // group-local staging id (256 threads per group)
    const int srow0 = ts >> 3, so0 = (ts & 7) * 16;
    const int srow1 = (ts + 256) >> 3, so1 = ((ts + 256) & 7) * 16;

    // Q as B-frag (lane holds Q[q = wq*16+col][d=8g..+8]), pre-scaled by log2e/8
    bf16x8 qf0, qf1;
    {
        const __bf16* qb = Qp + ((size_t)bh * S_LEN + qt * 64 + wq * 16 + col) * HD + g * 8;
        qf0 = *reinterpret_cast<const bf16x8*>(qb);
        qf1 = *reinterpret_cast<const bf16x8*>(qb + 32);
    }
    // O^T accumulator: lane holds O^T[d = 16nf+4g+r][q = col] over this group's kv
    f32x4 oacc[4];
    #pragma unroll
    for (int nf = 0; nf < 4; ++nf) oacc[nf] = (f32x4){0.f, 0.f, 0.f, 0.f};
    float m = -1e30f, lsum = 0.f;

    const int addrA = ((l & 15) + ((l & 16) << 1)) << 2;
    const int addrB = addrA + (16 << 2);
    const bool ghi = (l & 32) != 0;

    uint4 kr0, kr1, vr0, vr1;
    if (g2 <= qt) { // prologue: stage this group's first tile (t = g2)
        const unsigned char* kg = kgb + (size_t)g2 * 8192;
        const unsigned char* vg = vgb + (size_t)g2 * 128;
        kr0 = *reinterpret_cast<const uint4*>(kg + ts * 16);
        kr1 = *reinterpret_cast<const uint4*>(kg + (ts + 256) * 16);
        vr0 = *reinterpret_cast<const uint4*>(vg + (size_t)srow0 * (S_LEN * 2) + so0);
        vr1 = *reinterpret_cast<const uint4*>(vg + (size_t)srow1 * (S_LEN * 2) + so1);
        *reinterpret_cast<uint4*>(&kb[g2][swz(srow0 * 128 + so0, srow0)]) = kr0;
        *reinterpret_cast<uint4*>(&kb[g2][swz(srow1 * 128 + so1, srow1)]) = kr1;
        *reinterpret_cast<uint4*>(&vb[g2][swz(srow0 * 128 + so0, srow0)]) = vr0;
        *reinterpret_cast<uint4*>(&vb[g2][swz(srow1 * 128 + so1, srow1)]) = vr1;
    }
    __syncthreads();

    const int niter = (qt >> 1) + 1;
    #pragma unroll 1
    for (int i = 0; i < niter; ++i) {
        const int t = 2 * i + g2;           // this group's kv tile
        const bool active = (t <= qt);
        const int t2 = t + 2;
        const bool pfv = (t2 <= qt);
        if (pfv) { // issue next tile's loads now; latency hides under compute
            const unsigned char* kg = kgb + (size_t)t2 * 8192;
            const unsigned char* vg = vgb + (size_t)t2 * 128;
            kr0 = *reinterpret_cast<const uint4*>(kg + ts * 16);
            kr1 = *reinterpret_cast<const uint4*>(kg + (ts + 256) * 16);
            vr0 = *reinterpret_cast<const uint4*>(vg + (size_t)srow0 * (S_LEN * 2) + so0);
            vr1 = *reinterpret_cast<const uint4*>(vg + (size_t)srow1 * (S_LEN * 2) + so1);
        }
        if (active) {
            // S^T = K Q^T : lane holds S^T[kv = 16nf+4g+r][q = col]
            f32x4 sf[4];
            #pragma unroll
            for (int nf = 0; nf < 4; ++nf) sf[nf] = (f32x4){0.f, 0.f, 0.f, 0.f};
            #pragma unroll
            for (int nf = 0; nf < 4; ++nf) {
                int krow = nf * 16 + col;
                bf16x8 kf0 = *reinterpret_cast<const bf16x8*>(
                    &kb[g2][swz(krow * 128 + g * 16, krow)]);
                bf16x8 kf1 = *reinterpret_cast<const bf16x8*>(
                    &kb[g2][swz(krow * 128 + 64 + g * 16, krow)]);
                sf[nf] = __builtin_amdgcn_mfma_f32_16x16x32_bf16(kf0, qf0, sf[nf], 0, 0, 0);
                sf[nf] = __builtin_amdgcn_mfma_f32_16x16x32_bf16(kf1, qf1, sf[nf], 0, 0, 0);
            }
            if (t == qt) { // diagonal: mask kv_local > q_local (= wq*16 + col)
                const int qloc = wq * 16 + col;
                #pragma unroll
                for (int nf = 0; nf < 4; ++nf)
                    #pragma unroll
                    for (int r = 0; r < 4; ++r)
                        if (nf * 16 + g * 4 + r > qloc) sf[nf][r] = -1e30f;
            }
            float rmax = fmaxf(fmaxf(fmaxf(sf[0][0], sf[0][1]), fmaxf(sf[0][2], sf[0][3])),
                               fmaxf(fmaxf(sf[1][0], sf[1][1]), fmaxf(sf[1][2], sf[1][3])));
            rmax = fmaxf(rmax,
                   fmaxf(fmaxf(fmaxf(sf[2][0], sf[2][1]), fmaxf(sf[2][2], sf[2][3])),
                         fmaxf(fmaxf(sf[3][0], sf[3][1]), fmaxf(sf[3][2], sf[3][3]))));
            rmax = fmaxf(rmax, __shfl_xor(rmax, 16));
            rmax = fmaxf(rmax, __shfl_xor(rmax, 32));
            float mn = fmaxf(m, rmax);
            float sc = __builtin_exp2f(m - mn);
            m = mn;
            float rsum = 0.f;
            int wds[4][2];
            #pragma unroll
            for (int nf = 0; nf < 4; ++nf) {
                float p0 = __builtin_exp2f(sf[nf][0] - m);
                float p1 = __builtin_exp2f(sf[nf][1] - m);
                float p2 = __builtin_exp2f(sf[nf][2] - m);
                float p3 = __builtin_exp2f(sf[nf][3] - m);
                rsum += (p0 + p1) + (p2 + p3);
                asm("v_cvt_pk_bf16_f32 %0, %1, %2" : "=v"(wds[nf][0]) : "v"(p0), "v"(p1));
                asm("v_cvt_pk_bf16_f32 %0, %1, %2" : "=v"(wds[nf][1]) : "v"(p2), "v"(p3));
            }
            lsum = lsum * sc + rsum;
            // B-frag redistribution: pull both nf' candidates, select with ghi
            i32x4 bw0, bw1;
            #pragma unroll
            for (int j = 0; j < 4; ++j) {
                int a = (j < 2) ? addrA : addrB;
                int lo0 = __builtin_amdgcn_ds_bpermute(a, wds[0][j & 1]);
                int hi0 = __builtin_amdgcn_ds_bpermute(a, wds[1][j & 1]);
                int lo1 = __builtin_amdgcn_ds_bpermute(a, wds[2][j & 1]);
                int hi1 = __builtin_amdgcn_ds_bpermute(a, wds[3][j & 1]);
                bw0[j] = ghi ? hi0 : lo0;
                bw1[j] = ghi ? hi1 : lo1;
            }
            bf16x8 pf0, pf1;
            pf0 = *reinterpret_cast<bf16x8*>(&bw0);
            pf1 = *reinterpret_cast<bf16x8*>(&bw1);
            #pragma unroll
            for (int nf = 0; nf < 4; ++nf)
                #pragma unroll
                for (int r = 0; r < 4; ++r) oacc[nf][r] *= sc;
            #pragma unroll
            for (int nf = 0; nf < 4; ++nf) {
                int vrow = nf * 16 + col;
                bf16x8 vf0 = *reinterpret_cast<const bf16x8*>(
                    &vb[g2][swz(vrow * 128 + g * 16, vrow)]);
                bf16x8 vf1 = *reinterpret_cast<const bf16x8*>(
                    &vb[g2][swz(vrow * 128 + 64 + g * 16, vrow)]);
                oacc[nf] = __builtin_amdgcn_mfma_f32_16x16x32_bf16(vf0, pf0, oacc[nf], 0, 0, 0);
                oacc[nf] = __builtin_amdgcn_mfma_f32_16x16x32_bf16(vf1, pf1, oacc[nf], 0, 0, 0);
            }
        }
        __syncthreads(); // all reads of this buffer done
        if (pfv) {       // write-late: prefetched tile into the SAME buffer
            *reinterpret_cast<uint4*>(&kb[g2][swz(srow0 * 128 + so0, srow0)]) = kr0;
            *reinterpret_cast<uint4*>(&kb[g2][swz(srow1 * 128 + so1, srow1)]) = kr1;
            *reinterpret_cast<uint4*>(&vb[g2][swz(srow0 * 128 + so0, srow0)]) = vr0;
            *reinterpret_cast<uint4*>(&vb[g2][swz(srow1 * 128 + so1, srow1)]) = vr1;
        }
        __syncthreads(); // writes visible before next iter's reads
    }

    // flash partial-merge across the 2 kv groups (loop ended with a barrier,
    // so kb/vb are free to reuse; lane-contiguous layout = conflict-free)
    float* obuf = reinterpret_cast<float*>(&kb[0][0]); // 4096 f32 = 16 KB (all of kb)
    float* mbuf = reinterpret_cast<float*>(&vb[0][0]); // 512 f32
    const int lane256 = wq * 64 + l;
    if (g2 == 1) {
        #pragma unroll
        for (int nf = 0; nf < 4; ++nf)
            #pragma unroll
            for (int r = 0; r < 4; ++r)
                obuf[(nf * 4 + r) * 256 + lane256] = oacc[nf][r];
        mbuf[lane256] = m;
        mbuf[256 + lane256] = lsum;
    }
    __syncthreads();
    if (g2 == 0) {
        float mB = mbuf[lane256], lB = mbuf[256 + lane256];
        float M = fmaxf(m, mB);
        float eA = __builtin_exp2f(m - M);
        float eB = __builtin_exp2f(mB - M);
        lsum = eA * lsum + eB * lB;
        #pragma unroll
        for (int nf = 0; nf < 4; ++nf)
            #pragma unroll
            for (int r = 0; r < 4; ++r)
                oacc[nf][r] = eA * oacc[nf][r] + eB * obuf[(nf * 4 + r) * 256 + lane256];
        lsum += __shfl_xor(lsum, 16);
        lsum += __shfl_xor(lsum, 32);
        float inv = 1.0f / lsum;
        const int s = qt * 64 + wq * 16 + col;
        __bf16* op = Oa + ((size_t)b * S_LEN + s) * EMB + h * HD + g * 4;
        #pragma unroll
        for (int nf = 0; nf < 4; ++nf) {
            bf16x4 o;
            #pragma unroll
            for (int r = 0; r < 4; ++r) o[r] = (__bf16)(oacc[nf][r] * inv);
            *reinterpret_cast<bf16x4*>(op + nf * 16) = o;
        }
    }
}

__global__ __launch_bounds__(256) void fc_kernel(
    const __bf16* __restrict__ A,   // Oattn [B*S][E] bf16
    const float* __restrict__ Wfc,  // [E][E] fp32, row-major (n, k)
    const float* __restrict__ bfc,  // [E]
    float* __restrict__ out)        // [B*S][E] fp32
{
    __shared__ alignas(16) unsigned char ab[8192]; // A tile 64x64 bf16, swizzled
    __shared__ alignas(16) unsigned char bb[8192]; // W tile 64x64 bf16, swizzled
    const int r0 = blockIdx.x << 6;
    const int n0 = blockIdx.y << 6;
    const int tid = threadIdx.x;
    const int w = tid >> 6, l = tid & 63;
    const int col = l & 15, g = l >> 4;

    f32x4 acc[4];
    #pragma unroll
    for (int nf = 0; nf < 4; ++nf) acc[nf] = (f32x4){0.f, 0.f, 0.f, 0.f};

    for (int kc = 0; kc < 8; ++kc) {
        __syncthreads();
        #pragma unroll
        for (int it = 0; it < 2; ++it) {
            int c = tid + it * 256;
            int row = c >> 3, o = (c & 7) * 16;
            uint4 d = *reinterpret_cast<const uint4*>(
                reinterpret_cast<const unsigned char*>(A) +
                ((size_t)(r0 + row) * EMB + kc * 64) * 2 + o);
            *reinterpret_cast<uint4*>(&ab[swz(row * 128 + o, row)]) = d;
        }
        #pragma unroll
        for (int it = 0; it < 4; ++it) {
            int c = tid + it * 256;
            int row = c >> 4, c4 = c & 15;
            float4 f = *reinterpret_cast<const float4*>(
                Wfc + (size_t)(n0 + row) * EMB + kc * 64 + c4 * 4);
            bf16x4 t;
            t[0] = (__bf16)f.x; t[1] = (__bf16)f.y; t[2] = (__bf16)f.z; t[3] = (__bf16)f.w;
            *reinterpret_cast<bf16x4*>(&bb[swz(row * 128 + c4 * 8, row)]) = t;
        }
        __syncthreads();
        int arow = w * 16 + col;
        #pragma unroll
        for (int ks = 0; ks < 2; ++ks) {
            bf16x8 af = *reinterpret_cast<const bf16x8*>(
                &ab[swz(arow * 128 + ks * 64 + g * 16, arow)]);
            #pragma unroll
            for (int nf = 0; nf < 4; ++nf) {
                int brow = nf * 16 + col;
                bf16x8 bf = *reinterpret_cast<const bf16x8*>(
                    &bb[swz(brow * 128 + ks * 64 + g * 16, brow)]);
                acc[nf] = __builtin_amdgcn_mfma_f32_16x16x32_bf16(af, bf, acc[nf], 0, 0, 0);
            }
        }
    }
    #pragma unroll
    for (int nf = 0; nf < 4; ++nf) {
        float bias = bfc[n0 + nf * 16 + col];
        #pragma unroll
        for (int r = 0; r < 4; ++r) {
            int row = r0 + w * 16 + g * 4 + r;
            out[(size_t)row * EMB + n0 + nf * 16 + col] = acc[nf][r] + bias;
        }
    }
}

extern "C" void kernel_launch(void* const* d_in, const int* in_sizes, int n_in,
                              void* d_out, int out_size, void* d_ws, size_t ws_size,
                              hipStream_t stream) {
    const float* q   = (const float*)d_in[0];
    const float* k   = (const float*)d_in[1];
    const float* v   = (const float*)d_in[2];
    const float* Wq  = (const float*)d_in[3];
    const float* Wk  = (const float*)d_in[4];
    const float* Wv  = (const float*)d_in[5];
    const float* Wfc = (const float*)d_in[6];
    const float* bfc = (const float*)d_in[7];
    float* out = (float*)d_out;

    char* ws = (char*)d_ws;
    const size_t SZ = (size_t)4 * NH * S_LEN * HD * sizeof(__bf16); // 8 MiB
    __bf16* Qp = (__bf16*)(ws);
    __bf16* Kp = (__bf16*)(ws + SZ);
    __bf16* Vt = (__bf16*)(ws + 2 * SZ);
    __bf16* Oa = (__bf16*)(ws + 3 * SZ);

    proj_kernel<<<dim3(S_LEN / 64, 4 * NH), 256, 0, stream>>>(q, k, v, Wq, Wk, Wv, Qp, Kp, Vt);
    attn_kernel<<<dim3(32 * 32), 512, 0, stream>>>(Qp, Kp, Vt, Oa);
    fc_kernel<<<dim3((4 * S_LEN) / 64, EMB / 64), 256, 0, stream>>>(Oa, Wfc, bfc, out);
}